// Round 3
// baseline (7397.468 us; speedup 1.0000x reference)
//
#include <hip/hip_runtime.h>
#include <math.h>

// Problem constants (fixed by the reference module)
#define HSZ   512
#define H4    2048
#define SEQ   64
#define VOC   32000
#define BEAM  3
#define TMAX  50
#define NBLK  256
#define NTHR  256

#define LOFF  ((size_t)H4 * HSZ)   // per-layer weight stride

__device__ __forceinline__ float wsum(float v) {
#pragma unroll
  for (int off = 32; off; off >>= 1) v += __shfl_xor(v, off, 64);
  return v;
}
__device__ __forceinline__ float dot4(float4 a, float4 b) {
  return a.x * b.x + a.y * b.y + a.z * b.z + a.w * b.w;
}
__device__ __forceinline__ float sigf(float x) { return 1.f / (1.f + expf(-x)); }

__device__ __forceinline__ bool better(float v1, int i1, float v2, int i2) {
  return (v1 > v2) || (v1 == v2 && i1 < i2);  // jax.lax.top_k order: value desc, index asc
}
__device__ __forceinline__ void ins3(float* v, int* idx, float nv, int ni) {
  if (better(nv, ni, v[2], idx[2])) {
    if (better(nv, ni, v[1], idx[1])) {
      v[2] = v[1]; idx[2] = idx[1];
      if (better(nv, ni, v[0], idx[0])) { v[1] = v[0]; idx[1] = idx[0]; v[0] = nv; idx[0] = ni; }
      else { v[1] = nv; idx[1] = ni; }
    } else { v[2] = nv; idx[2] = ni; }
  }
}

// ---- software grid barrier (device-scope, graph-capture safe) ----
// grp: 16 counters on separate 128B lines (blocks blk%16==g form group g, 16 each).
// top: bumped once per group per barrier. Barrier b (1-based) completes at top==16*b.
// AGENT-scope atomics carry the L2 writeback/invalidate needed across XCDs.
__device__ __forceinline__ void gbar(int* grp, int* top, int b, int blk, int tid) {
  __syncthreads();
  if (tid == 0) {
    int v = __hip_atomic_fetch_add(&grp[(blk & 15) << 5], 1,
                                   __ATOMIC_ACQ_REL, __HIP_MEMORY_SCOPE_AGENT);
    if ((v & 15) == 15)
      __hip_atomic_fetch_add(top, 1, __ATOMIC_ACQ_REL, __HIP_MEMORY_SCOPE_AGENT);
    int target = b << 4;
    int it = 0;
    while (__hip_atomic_load(top, __ATOMIC_RELAXED, __HIP_MEMORY_SCOPE_AGENT) < target &&
           it < 20000000) {  // bailout: wrong answer beats a hang
      __builtin_amdgcn_s_sleep(2);
      ++it;
    }
    (void)__hip_atomic_load(top, __ATOMIC_ACQUIRE, __HIP_MEMORY_SCOPE_AGENT);
  }
  __syncthreads();
}

struct Ptrs {
  const int*   seq;
  const float* emb_enc; const float* Wih_enc; const float* Whh_enc; const float* b_enc;
  const float* emb_dec; const float* Wih_dec; const float* Whh_dec; const float* b_dec;
  const float* W_c; const float* W_out; const float* b_out;
  const int*   bosp;
  int* grp; int* top;
  float* emb_seq; float* xp1;
  float* h1a; float* c1a; float* h2a; float* c2a;
  float* hd; float* cd; float* hdn; float* cdn;
  float* x_dec; float* feat;
  float* pm; float* ps; float* pv; int* pi;
  float* scores; int* tokens; int* bt;
  int* outp;
};

// ---------------- encoder phases ----------------

__device__ void phase_init(const Ptrs& P, int blk, int tid) {
  if (blk < 64) {
    int tok = P.seq[blk];
    for (int e = tid; e < HSZ; e += NTHR) P.emb_seq[blk * HSZ + e] = P.emb_enc[tok * HSZ + e];
  } else if (blk < 68) {
    float* p = (blk == 64) ? P.h1a : (blk == 65) ? P.c1a : (blk == 66) ? P.h2a : P.c2a;
    for (int e = tid; e < HSZ; e += NTHR) p[e] = 0.f;
  }
}

// xp1[t][r] = b_enc[r] + dot(Wih_enc[r], emb_seq[t])
__device__ void phase_xw1(const Ptrs& P, int blk, int tid) {
  int t  = tid & 63;
  int rl = tid >> 6;
#pragma unroll
  for (int rr = 0; rr < 2; ++rr) {
    int r = blk * 8 + rl * 2 + rr;
    const float* wr = P.Wih_enc + (size_t)r * HSZ;
    const float* xr = P.emb_seq + t * HSZ;
    float acc = 0.f;
    for (int e = 0; e < HSZ; e += 4) {
      float4 wv = *(const float4*)(wr + e);
      float4 xv = *(const float4*)(xr + e);
      acc += dot4(wv, xv);
    }
    P.xp1[t * H4 + r] = acc + P.b_enc[r];
  }
}

// One wavefront slot: layer1 cell t=s (blocks 0..127), layer2 cell t=s-1 (blocks 128..255).
__device__ void phase_encslot(const Ptrs& P, int blk, int tid, int s) {
  int wave = __builtin_amdgcn_readfirstlane(tid >> 6);
  int lane = tid & 63;
  bool l2  = blk >= 128;
  int t    = l2 ? s - 1 : s;
  if (t < 0 || t >= SEQ) return;
  int j = (blk - (l2 ? 128 : 0)) * 4 + wave;  // 0..511
  float z[4];
  if (!l2) {
    const float4* h = (const float4*)(P.h1a + t * HSZ);
    float4 h0 = h[lane], h1v = h[lane + 64];
#pragma unroll
    for (int g = 0; g < 4; ++g) {
      int row = j + (g << 9);
      const float4* wr = (const float4*)(P.Whh_enc + (size_t)row * HSZ);
      float acc = dot4(wr[lane], h0) + dot4(wr[lane + 64], h1v);
      z[g] = wsum(acc) + P.xp1[t * H4 + row];
    }
    if (lane == 0) {
      float c = sigf(z[1]) * P.c1a[t * HSZ + j] + sigf(z[0]) * tanhf(z[2]);
      P.c1a[(t + 1) * HSZ + j] = c;
      P.h1a[(t + 1) * HSZ + j] = sigf(z[3]) * tanhf(c);
    }
  } else {
    const float4* x = (const float4*)(P.h1a + (t + 1) * HSZ);  // layer1 output at time t
    const float4* h = (const float4*)(P.h2a + t * HSZ);
    float4 x0 = x[lane], x1 = x[lane + 64], h0 = h[lane], h1v = h[lane + 64];
#pragma unroll
    for (int g = 0; g < 4; ++g) {
      int row = j + (g << 9);
      const float4* wi = (const float4*)(P.Wih_enc + LOFF + (size_t)row * HSZ);
      const float4* wh = (const float4*)(P.Whh_enc + LOFF + (size_t)row * HSZ);
      float acc = dot4(wi[lane], x0) + dot4(wi[lane + 64], x1) +
                  dot4(wh[lane], h0) + dot4(wh[lane + 64], h1v);
      z[g] = wsum(acc) + P.b_enc[H4 + row];
    }
    if (lane == 0) {
      float c = sigf(z[1]) * P.c2a[t * HSZ + j] + sigf(z[0]) * tanhf(z[2]);
      P.c2a[(t + 1) * HSZ + j] = c;
      P.h2a[(t + 1) * HSZ + j] = sigf(z[3]) * tanhf(c);
    }
  }
}

__device__ void phase_dinit(const Ptrs& P, int blk, int tid) {
  if (blk != 0) return;
  int bos = P.bosp[0];
  for (int e = tid; e < HSZ; e += NTHR) {
    P.hd[e]        = P.h1a[SEQ * HSZ + e];
    P.cd[e]        = P.c1a[SEQ * HSZ + e];
    P.hd[1536 + e] = P.h2a[SEQ * HSZ + e];
    P.cd[1536 + e] = P.c2a[SEQ * HSZ + e];
    P.x_dec[e]     = P.emb_dec[(size_t)bos * HSZ + e];
  }
}

// ---------------- decoder phases ----------------

template <int B>
__device__ void phase_dcell(const float* __restrict__ Wih, const float* __restrict__ Whh,
                            const float* __restrict__ bias, const float* __restrict__ x,
                            const float* __restrict__ hin, const float* __restrict__ cin,
                            float* __restrict__ hout, float* __restrict__ cout,
                            int blk, int tid) {
  if (blk >= 128) return;
  int wave = __builtin_amdgcn_readfirstlane(tid >> 6);
  int lane = tid & 63;
  int j = blk * 4 + wave;
  float4 xv[B][2], hv[B][2];
#pragma unroll
  for (int b = 0; b < B; ++b) {
    const float4* xb = (const float4*)(x + b * HSZ);
    const float4* hb = (const float4*)(hin + b * HSZ);
    xv[b][0] = xb[lane]; xv[b][1] = xb[lane + 64];
    hv[b][0] = hb[lane]; hv[b][1] = hb[lane + 64];
  }
  float z[4][B];
#pragma unroll
  for (int g = 0; g < 4; ++g) {
    int row = j + (g << 9);
    const float4* wi = (const float4*)(Wih + (size_t)row * HSZ);
    const float4* wh = (const float4*)(Whh + (size_t)row * HSZ);
    float4 wi0 = wi[lane], wi1 = wi[lane + 64], wh0 = wh[lane], wh1 = wh[lane + 64];
    float bb = bias[row];
#pragma unroll
    for (int b = 0; b < B; ++b) {
      float acc = dot4(wi0, xv[b][0]) + dot4(wi1, xv[b][1]) +
                  dot4(wh0, hv[b][0]) + dot4(wh1, hv[b][1]);
      z[g][b] = wsum(acc) + bb;
    }
  }
  if (lane == 0) {
#pragma unroll
    for (int b = 0; b < B; ++b) {
      float c = sigf(z[1][b]) * cin[b * HSZ + j] + sigf(z[0][b]) * tanhf(z[2][b]);
      cout[b * HSZ + j] = c;
      hout[b * HSZ + j] = sigf(z[3][b]) * tanhf(c);
    }
  }
}

// attention (redundant per block) + context + feat; blocks 0..127
template <int B>
__device__ void phase_attfeat(const Ptrs& P, int blk, int tid) {
  __shared__ float xs[BEAM * HSZ];
  __shared__ float at[BEAM * SEQ];
  __shared__ float xcs[BEAM * 1024];
  if (blk >= 128) return;  // block-uniform: whole block skips its __syncthreads
  const float* h2 = P.hdn + 1536;
  for (int i = tid; i < B * HSZ; i += NTHR) xs[i] = h2[i];
  __syncthreads();
  for (int i = tid; i < B * SEQ; i += NTHR) {
    int b = i >> 6, s2 = i & 63;
    const float* er = P.h2a + (s2 + 1) * HSZ;
    const float* xb = xs + b * HSZ;
    float acc = 0.f;
    for (int e = 0; e < HSZ; e += 4) {
      float4 ev = *(const float4*)(er + e);
      acc += ev.x * xb[e] + ev.y * xb[e + 1] + ev.z * xb[e + 2] + ev.w * xb[e + 3];
    }
    at[i] = acc;
  }
  __syncthreads();
  if (tid < B) {
    float m = -INFINITY;
    for (int s2 = 0; s2 < SEQ; ++s2) m = fmaxf(m, at[tid * SEQ + s2]);
    float s = 0.f;
    for (int s2 = 0; s2 < SEQ; ++s2) { float e = expf(at[tid * SEQ + s2] - m); at[tid * SEQ + s2] = e; s += e; }
    float inv = 1.f / s;
    for (int s2 = 0; s2 < SEQ; ++s2) at[tid * SEQ + s2] *= inv;
  }
  __syncthreads();
  // ctx: one coalesced pass over enc rows, all beams at once (threads 0..127)
  if (tid < 128) {
    int h4 = tid * 4;
    float4 acc[B];
#pragma unroll
    for (int b = 0; b < B; ++b) acc[b] = make_float4(0.f, 0.f, 0.f, 0.f);
    for (int s2 = 0; s2 < SEQ; ++s2) {
      float4 ev = *(const float4*)(P.h2a + (s2 + 1) * HSZ + h4);
#pragma unroll
      for (int b = 0; b < B; ++b) {
        float a = at[b * SEQ + s2];
        acc[b].x += a * ev.x; acc[b].y += a * ev.y; acc[b].z += a * ev.z; acc[b].w += a * ev.w;
      }
    }
#pragma unroll
    for (int b = 0; b < B; ++b) *(float4*)(xcs + b * 1024 + 512 + h4) = acc[b];
  }
  for (int i = tid; i < B * HSZ; i += NTHR) {
    int b = i >> 9, hcol = i & 511;
    xcs[b * 1024 + hcol] = xs[b * HSZ + hcol];
  }
  __syncthreads();
  // feat = tanh(xc @ W_c.T): wave j = blk*4+wave owns row j
  int wave = tid >> 6, lane = tid & 63;
  int j = blk * 4 + wave;
  const float4* w = (const float4*)(P.W_c + (size_t)j * 1024);
  float4 w0 = w[lane], w1 = w[lane + 64], w2 = w[lane + 128], w3 = w[lane + 192];
#pragma unroll
  for (int b = 0; b < B; ++b) {
    const float4* xb = (const float4*)(xcs + b * 1024);
    float acc = dot4(w0, xb[lane]) + dot4(w1, xb[lane + 64]) +
                dot4(w2, xb[lane + 128]) + dot4(w3, xb[lane + 192]);
    acc = wsum(acc);
    if (lane == 0) P.feat[b * HSZ + j] = tanhf(acc);
  }
}

// logits + streaming (max, sumexp, top3) per beam per block; all 256 blocks
template <int B>
__device__ void phase_logits(const Ptrs& P, int blk, int tid) {
  int wave = __builtin_amdgcn_readfirstlane(tid >> 6);
  int lane = tid & 63;
  int gid  = blk * 4 + wave;  // 0..1023
  float4 f0[B], f1[B];
#pragma unroll
  for (int b = 0; b < B; ++b) {
    const float4* fb = (const float4*)(P.feat + b * HSZ);
    f0[b] = fb[lane]; f1[b] = fb[lane + 64];
  }
  float m[B], ss[B], tv[B][3];
  int tix[B][3];
#pragma unroll
  for (int b = 0; b < B; ++b) {
    m[b] = -INFINITY; ss[b] = 0.f;
#pragma unroll
    for (int k = 0; k < 3; ++k) { tv[b][k] = -INFINITY; tix[b][k] = 0x7fffffff; }
  }
  for (int v = gid; v < VOC; v += 1024) {
    const float4* wr = (const float4*)(P.W_out + (size_t)v * HSZ);
    float4 w0 = wr[lane], w1 = wr[lane + 64];
    float bo = P.b_out[v];
#pragma unroll
    for (int b = 0; b < B; ++b) {
      float acc = dot4(w0, f0[b]) + dot4(w1, f1[b]);
      acc = wsum(acc) + bo;  // all lanes hold the logit (uniform)
      float mo = m[b], mn = fmaxf(mo, acc);
      ss[b] = ss[b] * expf(mo - mn) + expf(acc - mn);
      m[b]  = mn;
      ins3(tv[b], tix[b], acc, v);
    }
  }
  __shared__ float lm[4][3], lss[4][3], lv[4][3][3];
  __shared__ int li[4][3][3];
  if (lane == 0) {
#pragma unroll
    for (int b = 0; b < B; ++b) {
      lm[wave][b] = m[b]; lss[wave][b] = ss[b];
#pragma unroll
      for (int k = 0; k < 3; ++k) { lv[wave][b][k] = tv[b][k]; li[wave][b][k] = tix[b][k]; }
    }
  }
  __syncthreads();
  if (tid < B) {
    int b = tid;
    float M = fmaxf(fmaxf(lm[0][b], lm[1][b]), fmaxf(lm[2][b], lm[3][b]));
    float S = 0.f;
#pragma unroll
    for (int w2 = 0; w2 < 4; ++w2) S += lss[w2][b] * expf(lm[w2][b] - M);
    float bv[3] = {-INFINITY, -INFINITY, -INFINITY};
    int bi3[3]  = {0x7fffffff, 0x7fffffff, 0x7fffffff};
#pragma unroll
    for (int w2 = 0; w2 < 4; ++w2)
#pragma unroll
      for (int k = 0; k < 3; ++k) ins3(bv, bi3, lv[w2][b][k], li[w2][b][k]);
    int o = blk * 3 + b;
    P.pm[o] = M; P.ps[o] = S;
#pragma unroll
    for (int k = 0; k < 3; ++k) { P.pv[o * 3 + k] = bv[k]; P.pi[o * 3 + k] = bi3[k]; }
  }
  __syncthreads();
}

// final merge + beam bookkeeping; block 0 only
template <int B, int STEP0>
__device__ void phase_merge(const Ptrs& P, int blk, int tid, int ti) {
  __shared__ float sM[3], sS[3], sV[3][3], sScore[3];
  __shared__ int sI[3][3], sOrig[3], sTokNew[3], sTokOld[3], sKstar;
  if (blk != 0) return;  // block-uniform: block 0 only
  int wave = tid >> 6, lane = tid & 63;
  if (wave < B) {
    int b = wave;
    float lm4[4], ls4[4];
    float M = -INFINITY;
#pragma unroll
    for (int q = 0; q < 4; ++q) {
      int blk2 = lane + q * 64;
      lm4[q] = P.pm[blk2 * 3 + b]; ls4[q] = P.ps[blk2 * 3 + b];
      M = fmaxf(M, lm4[q]);
    }
#pragma unroll
    for (int off = 32; off; off >>= 1) M = fmaxf(M, __shfl_xor(M, off, 64));
    float S = 0.f;
#pragma unroll
    for (int q = 0; q < 4; ++q) S += ls4[q] * expf(lm4[q] - M);
    S = wsum(S);
    float bv[3] = {-INFINITY, -INFINITY, -INFINITY};
    int bi3[3]  = {0x7fffffff, 0x7fffffff, 0x7fffffff};
#pragma unroll
    for (int q = 0; q < 4; ++q) {
      int blk2 = lane + q * 64;
#pragma unroll
      for (int k = 0; k < 3; ++k)
        ins3(bv, bi3, P.pv[(blk2 * 3 + b) * 3 + k], P.pi[(blk2 * 3 + b) * 3 + k]);
    }
#pragma unroll
    for (int off = 32; off; off >>= 1) {
      float ov[3]; int oi[3];
#pragma unroll
      for (int k = 0; k < 3; ++k) { ov[k] = __shfl_xor(bv[k], off, 64); oi[k] = __shfl_xor(bi3[k], off, 64); }
#pragma unroll
      for (int k = 0; k < 3; ++k) ins3(bv, bi3, ov[k], oi[k]);
    }
    if (lane == 0) {
      sM[b] = M; sS[b] = S;
#pragma unroll
      for (int k = 0; k < 3; ++k) { sV[b][k] = bv[k]; sI[b][k] = bi3[k]; }
    }
  }
  __syncthreads();
  if (tid == 0) {
    if (STEP0) {
      float off0 = -sM[0] - logf(sS[0]);
      for (int k = 0; k < 3; ++k) {
        sScore[k] = sV[0][k] + off0;
        sTokNew[k] = sI[0][k]; sOrig[k] = 0; sTokOld[k] = 0;
        P.scores[k] = sScore[k]; P.tokens[k] = sTokNew[k];
      }
    } else {
      float osc[3]; int otk[3];
      for (int b = 0; b < 3; ++b) { osc[b] = P.scores[b]; otk[b] = P.tokens[b]; sTokOld[b] = otk[b]; }
      float cum[9];
      for (int b = 0; b < 3; ++b) {
        float o = osc[b] - sM[b] - logf(sS[b]);
        for (int k = 0; k < 3; ++k) cum[b * 3 + k] = sV[b][k] + o;
      }
      bool used[9] = {false, false, false, false, false, false, false, false, false};
      for (int k = 0; k < 3; ++k) {
        int bf = 0; float bb = -INFINITY;
        for (int f = 0; f < 9; ++f)
          if (!used[f] && cum[f] > bb) { bb = cum[f]; bf = f; }  // strict > keeps lowest flat idx on tie
        used[bf] = true;
        sScore[k] = bb;
        int ob = bf / 3;
        sOrig[k] = ob;
        sTokNew[k] = sI[ob][bf - ob * 3];
      }
      for (int k = 0; k < 3; ++k) { P.scores[k] = sScore[k]; P.tokens[k] = sTokNew[k]; }
    }
    float bb = -INFINITY; int kk = 0;
    for (int k = 0; k < 3; ++k) if (sScore[k] > bb) { bb = sScore[k]; kk = k; }
    sKstar = kk;
  }
  __syncthreads();
  // permute h,c into current-state buffers for next step
  for (int idx = tid; idx < 2 * 3 * HSZ; idx += NTHR) {
    int l = idx / 1536, rem = idx % 1536, k = rem / HSZ, e = rem & 511;
    int o = STEP0 ? 0 : sOrig[k];
    P.hd[l * 1536 + k * HSZ + e] = P.hdn[l * 1536 + o * HSZ + e];
    P.cd[l * 1536 + k * HSZ + e] = P.cdn[l * 1536 + o * HSZ + e];
  }
  if (STEP0) {
    int bos = P.bosp[0];
    for (int idx = tid; idx < BEAM * TMAX; idx += NTHR) P.bt[idx] = bos;  // buffer 0
  } else {
    const int* src = P.bt + (ti & 1) * (BEAM * TMAX);
    int* dst = P.bt + ((ti + 1) & 1) * (BEAM * TMAX);
    for (int idx = tid; idx < BEAM * TMAX; idx += NTHR) {
      int k = idx / TMAX, jj = idx % TMAX, o = sOrig[k];
      dst[idx] = (jj == ti + 1) ? sTokOld[o] : src[o * TMAX + jj];
    }
  }
  for (int idx = tid; idx < BEAM * HSZ; idx += NTHR) {
    int k = idx >> 9, e = idx & 511;
    P.x_dec[idx] = P.emb_dec[(size_t)sTokNew[k] * HSZ + e];
  }
  if (!STEP0 && ti == TMAX - 2) {
    __syncthreads();
    const int* dst = P.bt + ((ti + 1) & 1) * (BEAM * TMAX);
    for (int jj = tid; jj < TMAX; jj += 256) P.outp[jj] = dst[sKstar * TMAX + jj];
  }
}

template <int B, int STEP0>
__device__ void dstep(const Ptrs& P, int blk, int tid, int& nb, int ti) {
  phase_dcell<B>(P.Wih_dec, P.Whh_dec, P.b_dec, P.x_dec, P.hd, P.cd, P.hdn, P.cdn, blk, tid);
  gbar(P.grp, P.top, ++nb, blk, tid);
  phase_dcell<B>(P.Wih_dec + LOFF, P.Whh_dec + LOFF, P.b_dec + H4,
                 P.hdn, P.hd + 1536, P.cd + 1536, P.hdn + 1536, P.cdn + 1536, blk, tid);
  gbar(P.grp, P.top, ++nb, blk, tid);
  phase_attfeat<B>(P, blk, tid);
  gbar(P.grp, P.top, ++nb, blk, tid);
  phase_logits<B>(P, blk, tid);
  gbar(P.grp, P.top, ++nb, blk, tid);
  phase_merge<B, STEP0>(P, blk, tid, ti);
  gbar(P.grp, P.top, ++nb, blk, tid);
}

__global__ void __launch_bounds__(NTHR, 1) mega(Ptrs P) {
  int blk = blockIdx.x, tid = threadIdx.x;
  int nb = 0;

  phase_init(P, blk, tid);
  gbar(P.grp, P.top, ++nb, blk, tid);
  phase_xw1(P, blk, tid);
  gbar(P.grp, P.top, ++nb, blk, tid);
  for (int s = 0; s <= SEQ; ++s) {
    phase_encslot(P, blk, tid, s);
    gbar(P.grp, P.top, ++nb, blk, tid);
  }
  phase_dinit(P, blk, tid);
  gbar(P.grp, P.top, ++nb, blk, tid);

  for (int step = 0; step < TMAX; ++step) {
    if (step == 0) dstep<1, 1>(P, blk, tid, nb, -1);
    else           dstep<3, 0>(P, blk, tid, nb, step - 1);
  }
}

extern "C" void kernel_launch(void* const* d_in, const int* in_sizes, int n_in,
                              void* d_out, int out_size, void* d_ws, size_t ws_size,
                              hipStream_t stream) {
  Ptrs P;
  P.seq     = (const int*)d_in[0];
  P.emb_enc = (const float*)d_in[1];
  P.Wih_enc = (const float*)d_in[2];
  P.Whh_enc = (const float*)d_in[3];
  P.b_enc   = (const float*)d_in[4];
  P.emb_dec = (const float*)d_in[5];
  P.Wih_dec = (const float*)d_in[6];
  P.Whh_dec = (const float*)d_in[7];
  P.b_dec   = (const float*)d_in[8];
  P.W_c     = (const float*)d_in[9];
  P.W_out   = (const float*)d_in[10];
  P.b_out   = (const float*)d_in[11];
  P.bosp    = (const int*)d_in[14];

  // barrier region first (4 KB), zeroed every call
  P.grp = (int*)d_ws;            // 16 counters at 128B stride
  P.top = (int*)d_ws + 512;

  float* w = (float*)d_ws + 1024;
  P.emb_seq = w; w += SEQ * HSZ;
  P.xp1     = w; w += SEQ * H4;
  P.h1a     = w; w += (SEQ + 1) * HSZ;
  P.c1a     = w; w += (SEQ + 1) * HSZ;
  P.h2a     = w; w += (SEQ + 1) * HSZ;
  P.c2a     = w; w += (SEQ + 1) * HSZ;
  P.hd      = w; w += 2 * BEAM * HSZ;
  P.cd      = w; w += 2 * BEAM * HSZ;
  P.hdn     = w; w += 2 * BEAM * HSZ;
  P.cdn     = w; w += 2 * BEAM * HSZ;
  P.x_dec   = w; w += BEAM * HSZ;
  P.feat    = w; w += BEAM * HSZ;
  P.pm      = w; w += NBLK * 3;
  P.ps      = w; w += NBLK * 3;
  P.pv      = w; w += NBLK * 3 * 3;
  P.scores  = w; w += 4;
  P.pi      = (int*)w; w += NBLK * 3 * 3;
  P.tokens  = (int*)w; w += 4;
  P.bt      = (int*)w; w += 2 * BEAM * TMAX + 4;
  P.outp    = (int*)d_out;

  hipMemsetAsync(d_ws, 0, 4096, stream);
  mega<<<dim3(NBLK), dim3(NTHR), 0, stream>>>(P);
}

// Round 4
// 6554.478 us; speedup vs baseline: 1.1286x; 1.1286x over previous
//
#include <hip/hip_runtime.h>
#include <math.h>

// Problem constants (fixed by the reference module)
#define HSZ   512
#define H4    2048
#define SEQ   64
#define VOC   32000
#define BEAM  3
#define TMAX  50
#define NBLK  256
#define NTHR  256
#define FLS   16        // flag line stride in ints (64 B)

#define LOFF  ((size_t)H4 * HSZ)   // per-layer weight stride

__device__ __forceinline__ float wsum(float v) {
#pragma unroll
  for (int off = 32; off; off >>= 1) v += __shfl_xor(v, off, 64);
  return v;
}
__device__ __forceinline__ float dot4(float4 a, float4 b) {
  return a.x * b.x + a.y * b.y + a.z * b.z + a.w * b.w;
}
__device__ __forceinline__ float sigf(float x) { return 1.f / (1.f + expf(-x)); }

__device__ __forceinline__ bool better(float v1, int i1, float v2, int i2) {
  return (v1 > v2) || (v1 == v2 && i1 < i2);  // jax.lax.top_k order: value desc, index asc
}
__device__ __forceinline__ void ins3(float* v, int* idx, float nv, int ni) {
  if (better(nv, ni, v[2], idx[2])) {
    if (better(nv, ni, v[1], idx[1])) {
      v[2] = v[1]; idx[2] = idx[1];
      if (better(nv, ni, v[0], idx[0])) { v[1] = v[0]; idx[1] = idx[0]; v[0] = nv; idx[0] = ni; }
      else { v[1] = nv; idx[1] = ni; }
    } else { v[2] = nv; idx[2] = ni; }
  }
}

// ---- fast software grid barrier: per-block flag lines + block0 collect + go broadcast ----
// hb chain: arriver release-stores flags[blk]; block0 acquire-loads all flags (256 threads
// in parallel); block0 release-stores 16 go lines; others acquire go[blk&15].
__device__ __forceinline__ void bar_arrive(int* flags, int blk, int tid, int ep) {
  __syncthreads();  // all block writes issued (vmcnt drained per-wave at barrier)
  if (tid == 0)
    __hip_atomic_store(&flags[blk * FLS], ep, __ATOMIC_RELEASE, __HIP_MEMORY_SCOPE_AGENT);
}
__device__ __forceinline__ void bar_collect(int* flags, int tid, int ep) {
  int it = 0;
  while (__hip_atomic_load(&flags[tid * FLS], __ATOMIC_RELAXED, __HIP_MEMORY_SCOPE_AGENT) < ep &&
         it < 50000000) ++it;  // bailout: wrong answer beats a hang
  (void)__hip_atomic_load(&flags[tid * FLS], __ATOMIC_ACQUIRE, __HIP_MEMORY_SCOPE_AGENT);
  __syncthreads();
}
__device__ __forceinline__ void bar_release(int* go, int tid, int ep) {
  if (tid < 16)
    __hip_atomic_store(&go[tid * FLS], ep, __ATOMIC_RELEASE, __HIP_MEMORY_SCOPE_AGENT);
}
__device__ __forceinline__ void bar_waitgo(int* go, int blk, int tid, int ep) {
  if (tid == 0) {
    int it = 0;
    while (__hip_atomic_load(&go[(blk & 15) * FLS], __ATOMIC_RELAXED, __HIP_MEMORY_SCOPE_AGENT) < ep &&
           it < 50000000) { __builtin_amdgcn_s_sleep(1); ++it; }
    (void)__hip_atomic_load(&go[(blk & 15) * FLS], __ATOMIC_ACQUIRE, __HIP_MEMORY_SCOPE_AGENT);
  }
  __syncthreads();
}

struct Ptrs {
  const int*   seq;
  const float* emb_enc; const float* Wih_enc; const float* Whh_enc; const float* b_enc;
  const float* emb_dec; const float* Wih_dec; const float* Whh_dec; const float* b_dec;
  const float* W_c; const float* W_out; const float* b_out;
  const int*   bosp;
  int* flags; int* go;
  float* xp1;
  float* h1a; float* c1a; float* h2a; float* c2a;
  float* hd; float* cd; float* hdn; float* cdn;
  float* x_dec; float* feat;
  float* pm; float* ps; float* pv; int* pi;
  float* scores; int* tokens; int* bt;
  int* outp;
};

__device__ __forceinline__ void gbar(const Ptrs& P, int blk, int tid, int ep) {
  bar_arrive(P.flags, blk, tid, ep);
  if (blk == 0) {
    bar_collect(P.flags, tid, ep);
    bar_release(P.go, tid, ep);
  } else {
    bar_waitgo(P.go, blk, tid, ep);
  }
}

// ---------------- encoder phases ----------------

// xp1[t][r] = b_enc[r] + dot(Wih_enc[r], emb_enc[seq[t]])  (gathers embedding directly)
__device__ void phase_xw1(const Ptrs& P, int blk, int tid) {
  int t  = tid & 63;
  int rl = tid >> 6;
  int tok = P.seq[t];
  const float* xr = P.emb_enc + (size_t)tok * HSZ;
#pragma unroll
  for (int rr = 0; rr < 2; ++rr) {
    int r = blk * 8 + rl * 2 + rr;
    const float* wr = P.Wih_enc + (size_t)r * HSZ;
    float acc = 0.f;
    for (int e = 0; e < HSZ; e += 4) {
      float4 wv = *(const float4*)(wr + e);
      float4 xv = *(const float4*)(xr + e);
      acc += dot4(wv, xv);
    }
    P.xp1[t * H4 + r] = acc + P.b_enc[r];
  }
}

// One wavefront slot: layer1 cell t=s (blocks 0..127), layer2 cell t=s-1 (blocks 128..255).
// State rows: row t = state after t steps; t==0 state is implicit zeros (rows 0 never touched).
__device__ void phase_encslot(const Ptrs& P, int blk, int tid, int s) {
  int wave = __builtin_amdgcn_readfirstlane(tid >> 6);
  int lane = tid & 63;
  bool l2  = blk >= 128;
  int t    = l2 ? s - 1 : s;
  if (t < 0 || t >= SEQ) return;
  int j = (blk - (l2 ? 128 : 0)) * 4 + wave;  // 0..511
  float4 zf4 = make_float4(0.f, 0.f, 0.f, 0.f);
  float z[4];
  if (!l2) {
    float4 h0 = zf4, h1v = zf4;
    if (t > 0) {
      const float4* h = (const float4*)(P.h1a + t * HSZ);
      h0 = h[lane]; h1v = h[lane + 64];
    }
#pragma unroll
    for (int g = 0; g < 4; ++g) {
      int row = j + (g << 9);
      const float4* wr = (const float4*)(P.Whh_enc + (size_t)row * HSZ);
      float acc = dot4(wr[lane], h0) + dot4(wr[lane + 64], h1v);
      z[g] = wsum(acc) + P.xp1[t * H4 + row];
    }
    if (lane == 0) {
      float cp = (t > 0) ? P.c1a[t * HSZ + j] : 0.f;
      float c = sigf(z[1]) * cp + sigf(z[0]) * tanhf(z[2]);
      P.c1a[(t + 1) * HSZ + j] = c;
      P.h1a[(t + 1) * HSZ + j] = sigf(z[3]) * tanhf(c);
    }
  } else {
    const float4* x = (const float4*)(P.h1a + (t + 1) * HSZ);  // layer1 output at time t
    float4 x0 = x[lane], x1 = x[lane + 64];
    float4 h0 = zf4, h1v = zf4;
    if (t > 0) {
      const float4* h = (const float4*)(P.h2a + t * HSZ);
      h0 = h[lane]; h1v = h[lane + 64];
    }
#pragma unroll
    for (int g = 0; g < 4; ++g) {
      int row = j + (g << 9);
      const float4* wi = (const float4*)(P.Wih_enc + LOFF + (size_t)row * HSZ);
      const float4* wh = (const float4*)(P.Whh_enc + LOFF + (size_t)row * HSZ);
      float acc = dot4(wi[lane], x0) + dot4(wi[lane + 64], x1) +
                  dot4(wh[lane], h0) + dot4(wh[lane + 64], h1v);
      z[g] = wsum(acc) + P.b_enc[H4 + row];
    }
    if (lane == 0) {
      float cp = (t > 0) ? P.c2a[t * HSZ + j] : 0.f;
      float c = sigf(z[1]) * cp + sigf(z[0]) * tanhf(z[2]);
      P.c2a[(t + 1) * HSZ + j] = c;
      P.h2a[(t + 1) * HSZ + j] = sigf(z[3]) * tanhf(c);
    }
  }
}

// run by block 0 inside the last encoder slot's barrier
__device__ void dinit_body(const Ptrs& P, int tid) {
  int bos = P.bosp[0];
  for (int e = tid; e < HSZ; e += NTHR) {
    P.hd[e]        = P.h1a[SEQ * HSZ + e];
    P.cd[e]        = P.c1a[SEQ * HSZ + e];
    P.hd[1536 + e] = P.h2a[SEQ * HSZ + e];
    P.cd[1536 + e] = P.c2a[SEQ * HSZ + e];
    P.x_dec[e]     = P.emb_dec[(size_t)bos * HSZ + e];
  }
}

// ---------------- decoder phases ----------------

template <int B>
__device__ void phase_dcell(const float* __restrict__ Wih, const float* __restrict__ Whh,
                            const float* __restrict__ bias, const float* __restrict__ x,
                            const float* __restrict__ hin, const float* __restrict__ cin,
                            float* __restrict__ hout, float* __restrict__ cout,
                            int blk, int tid) {
  if (blk >= 128) return;
  int wave = __builtin_amdgcn_readfirstlane(tid >> 6);
  int lane = tid & 63;
  int j = blk * 4 + wave;
  float4 xv[B][2], hv[B][2];
#pragma unroll
  for (int b = 0; b < B; ++b) {
    const float4* xb = (const float4*)(x + b * HSZ);
    const float4* hb = (const float4*)(hin + b * HSZ);
    xv[b][0] = xb[lane]; xv[b][1] = xb[lane + 64];
    hv[b][0] = hb[lane]; hv[b][1] = hb[lane + 64];
  }
  float z[4][B];
#pragma unroll
  for (int g = 0; g < 4; ++g) {
    int row = j + (g << 9);
    const float4* wi = (const float4*)(Wih + (size_t)row * HSZ);
    const float4* wh = (const float4*)(Whh + (size_t)row * HSZ);
    float4 wi0 = wi[lane], wi1 = wi[lane + 64], wh0 = wh[lane], wh1 = wh[lane + 64];
    float bb = bias[row];
#pragma unroll
    for (int b = 0; b < B; ++b) {
      float acc = dot4(wi0, xv[b][0]) + dot4(wi1, xv[b][1]) +
                  dot4(wh0, hv[b][0]) + dot4(wh1, hv[b][1]);
      z[g][b] = wsum(acc) + bb;
    }
  }
  if (lane == 0) {
#pragma unroll
    for (int b = 0; b < B; ++b) {
      float c = sigf(z[1][b]) * cin[b * HSZ + j] + sigf(z[0][b]) * tanhf(z[2][b]);
      cout[b * HSZ + j] = c;
      hout[b * HSZ + j] = sigf(z[3][b]) * tanhf(c);
    }
  }
}

// attention (redundant per block) + context + feat; blocks 0..127
template <int B>
__device__ void phase_attfeat(const Ptrs& P, int blk, int tid) {
  __shared__ float xs[BEAM * HSZ];
  __shared__ float at[BEAM * SEQ];
  __shared__ float xcs[BEAM * 1024];
  if (blk >= 128) return;  // block-uniform: whole block skips its __syncthreads
  const float* h2 = P.hdn + 1536;
  for (int i = tid; i < B * HSZ; i += NTHR) xs[i] = h2[i];
  __syncthreads();
  for (int i = tid; i < B * SEQ; i += NTHR) {
    int b = i >> 6, s2 = i & 63;
    const float* er = P.h2a + (s2 + 1) * HSZ;
    const float* xb = xs + b * HSZ;
    float acc = 0.f;
    for (int e = 0; e < HSZ; e += 4) {
      float4 ev = *(const float4*)(er + e);
      acc += ev.x * xb[e] + ev.y * xb[e + 1] + ev.z * xb[e + 2] + ev.w * xb[e + 3];
    }
    at[i] = acc;
  }
  __syncthreads();
  if (tid < B) {
    float m = -INFINITY;
    for (int s2 = 0; s2 < SEQ; ++s2) m = fmaxf(m, at[tid * SEQ + s2]);
    float s = 0.f;
    for (int s2 = 0; s2 < SEQ; ++s2) { float e = expf(at[tid * SEQ + s2] - m); at[tid * SEQ + s2] = e; s += e; }
    float inv = 1.f / s;
    for (int s2 = 0; s2 < SEQ; ++s2) at[tid * SEQ + s2] *= inv;
  }
  __syncthreads();
  if (tid < 128) {
    int h4 = tid * 4;
    float4 acc[B];
#pragma unroll
    for (int b = 0; b < B; ++b) acc[b] = make_float4(0.f, 0.f, 0.f, 0.f);
    for (int s2 = 0; s2 < SEQ; ++s2) {
      float4 ev = *(const float4*)(P.h2a + (s2 + 1) * HSZ + h4);
#pragma unroll
      for (int b = 0; b < B; ++b) {
        float a = at[b * SEQ + s2];
        acc[b].x += a * ev.x; acc[b].y += a * ev.y; acc[b].z += a * ev.z; acc[b].w += a * ev.w;
      }
    }
#pragma unroll
    for (int b = 0; b < B; ++b) *(float4*)(xcs + b * 1024 + 512 + h4) = acc[b];
  }
  for (int i = tid; i < B * HSZ; i += NTHR) {
    int b = i >> 9, hcol = i & 511;
    xcs[b * 1024 + hcol] = xs[b * HSZ + hcol];
  }
  __syncthreads();
  int wave = tid >> 6, lane = tid & 63;
  int j = blk * 4 + wave;
  const float4* w = (const float4*)(P.W_c + (size_t)j * 1024);
  float4 w0 = w[lane], w1 = w[lane + 64], w2 = w[lane + 128], w3 = w[lane + 192];
#pragma unroll
  for (int b = 0; b < B; ++b) {
    const float4* xb = (const float4*)(xcs + b * 1024);
    float acc = dot4(w0, xb[lane]) + dot4(w1, xb[lane + 64]) +
                dot4(w2, xb[lane + 128]) + dot4(w3, xb[lane + 192]);
    acc = wsum(acc);
    if (lane == 0) P.feat[b * HSZ + j] = tanhf(acc);
  }
}

// logits + streaming (max, sumexp, top3) per beam per block; all 256 blocks
template <int B>
__device__ void phase_logits(const Ptrs& P, int blk, int tid) {
  int wave = __builtin_amdgcn_readfirstlane(tid >> 6);
  int lane = tid & 63;
  int gid  = blk * 4 + wave;  // 0..1023
  float4 f0[B], f1[B];
#pragma unroll
  for (int b = 0; b < B; ++b) {
    const float4* fb = (const float4*)(P.feat + b * HSZ);
    f0[b] = fb[lane]; f1[b] = fb[lane + 64];
  }
  float m[B], ss[B], tv[B][3];
  int tix[B][3];
#pragma unroll
  for (int b = 0; b < B; ++b) {
    m[b] = -INFINITY; ss[b] = 0.f;
#pragma unroll
    for (int k = 0; k < 3; ++k) { tv[b][k] = -INFINITY; tix[b][k] = 0x7fffffff; }
  }
  for (int v = gid; v < VOC; v += 1024) {
    const float4* wr = (const float4*)(P.W_out + (size_t)v * HSZ);
    float4 w0 = wr[lane], w1 = wr[lane + 64];
    float bo = P.b_out[v];
#pragma unroll
    for (int b = 0; b < B; ++b) {
      float acc = dot4(w0, f0[b]) + dot4(w1, f1[b]);
      acc = wsum(acc) + bo;  // all lanes hold the logit (uniform)
      float mo = m[b], mn = fmaxf(mo, acc);
      ss[b] = ss[b] * expf(mo - mn) + expf(acc - mn);
      m[b]  = mn;
      ins3(tv[b], tix[b], acc, v);
    }
  }
  __shared__ float lm[4][3], lss[4][3], lv[4][3][3];
  __shared__ int li[4][3][3];
  if (lane == 0) {
#pragma unroll
    for (int b = 0; b < B; ++b) {
      lm[wave][b] = m[b]; lss[wave][b] = ss[b];
#pragma unroll
      for (int k = 0; k < 3; ++k) { lv[wave][b][k] = tv[b][k]; li[wave][b][k] = tix[b][k]; }
    }
  }
  __syncthreads();
  if (tid < B) {
    int b = tid;
    float M = fmaxf(fmaxf(lm[0][b], lm[1][b]), fmaxf(lm[2][b], lm[3][b]));
    float S = 0.f;
#pragma unroll
    for (int w2 = 0; w2 < 4; ++w2) S += lss[w2][b] * expf(lm[w2][b] - M);
    float bv[3] = {-INFINITY, -INFINITY, -INFINITY};
    int bi3[3]  = {0x7fffffff, 0x7fffffff, 0x7fffffff};
#pragma unroll
    for (int w2 = 0; w2 < 4; ++w2)
#pragma unroll
      for (int k = 0; k < 3; ++k) ins3(bv, bi3, lv[w2][b][k], li[w2][b][k]);
    int o = blk * 3 + b;
    P.pm[o] = M; P.ps[o] = S;
#pragma unroll
    for (int k = 0; k < 3; ++k) { P.pv[o * 3 + k] = bv[k]; P.pi[o * 3 + k] = bi3[k]; }
  }
}

// final merge + beam bookkeeping; run by block 0's 256 threads inside the logits barrier
template <int B, int STEP0>
__device__ void merge_body(const Ptrs& P, int tid, int ti) {
  __shared__ float sM[3], sS[3], sV[3][3], sScore[3];
  __shared__ int sI[3][3], sOrig[3], sTokNew[3], sTokOld[3], sKstar;
  int wave = tid >> 6, lane = tid & 63;
  if (wave < B) {
    int b = wave;
    float lm4[4], ls4[4];
    float M = -INFINITY;
#pragma unroll
    for (int q = 0; q < 4; ++q) {
      int blk2 = lane + q * 64;
      lm4[q] = P.pm[blk2 * 3 + b]; ls4[q] = P.ps[blk2 * 3 + b];
      M = fmaxf(M, lm4[q]);
    }
#pragma unroll
    for (int off = 32; off; off >>= 1) M = fmaxf(M, __shfl_xor(M, off, 64));
    float S = 0.f;
#pragma unroll
    for (int q = 0; q < 4; ++q) S += ls4[q] * expf(lm4[q] - M);
    S = wsum(S);
    float bv[3] = {-INFINITY, -INFINITY, -INFINITY};
    int bi3[3]  = {0x7fffffff, 0x7fffffff, 0x7fffffff};
#pragma unroll
    for (int q = 0; q < 4; ++q) {
      int blk2 = lane + q * 64;
#pragma unroll
      for (int k = 0; k < 3; ++k)
        ins3(bv, bi3, P.pv[(blk2 * 3 + b) * 3 + k], P.pi[(blk2 * 3 + b) * 3 + k]);
    }
#pragma unroll
    for (int off = 32; off; off >>= 1) {
      float ov[3]; int oi[3];
#pragma unroll
      for (int k = 0; k < 3; ++k) { ov[k] = __shfl_xor(bv[k], off, 64); oi[k] = __shfl_xor(bi3[k], off, 64); }
#pragma unroll
      for (int k = 0; k < 3; ++k) ins3(bv, bi3, ov[k], oi[k]);
    }
    if (lane == 0) {
      sM[b] = M; sS[b] = S;
#pragma unroll
      for (int k = 0; k < 3; ++k) { sV[b][k] = bv[k]; sI[b][k] = bi3[k]; }
    }
  }
  __syncthreads();
  if (tid == 0) {
    if (STEP0) {
      float off0 = -sM[0] - logf(sS[0]);
      for (int k = 0; k < 3; ++k) {
        sScore[k] = sV[0][k] + off0;
        sTokNew[k] = sI[0][k]; sOrig[k] = 0; sTokOld[k] = 0;
        P.scores[k] = sScore[k]; P.tokens[k] = sTokNew[k];
      }
    } else {
      float osc[3]; int otk[3];
      for (int b = 0; b < 3; ++b) { osc[b] = P.scores[b]; otk[b] = P.tokens[b]; sTokOld[b] = otk[b]; }
      float cum[9];
      for (int b = 0; b < 3; ++b) {
        float o = osc[b] - sM[b] - logf(sS[b]);
        for (int k = 0; k < 3; ++k) cum[b * 3 + k] = sV[b][k] + o;
      }
      bool used[9] = {false, false, false, false, false, false, false, false, false};
      for (int k = 0; k < 3; ++k) {
        int bf = 0; float bb = -INFINITY;
        for (int f = 0; f < 9; ++f)
          if (!used[f] && cum[f] > bb) { bb = cum[f]; bf = f; }  // strict > keeps lowest flat idx on tie
        used[bf] = true;
        sScore[k] = bb;
        int ob = bf / 3;
        sOrig[k] = ob;
        sTokNew[k] = sI[ob][bf - ob * 3];
      }
      for (int k = 0; k < 3; ++k) { P.scores[k] = sScore[k]; P.tokens[k] = sTokNew[k]; }
    }
    float bb = -INFINITY; int kk = 0;
    for (int k = 0; k < 3; ++k) if (sScore[k] > bb) { bb = sScore[k]; kk = k; }
    sKstar = kk;
  }
  __syncthreads();
  for (int idx = tid; idx < 2 * 3 * HSZ; idx += NTHR) {
    int l = idx / 1536, rem = idx % 1536, k = rem / HSZ, e = rem & 511;
    int o = STEP0 ? 0 : sOrig[k];
    P.hd[l * 1536 + k * HSZ + e] = P.hdn[l * 1536 + o * HSZ + e];
    P.cd[l * 1536 + k * HSZ + e] = P.cdn[l * 1536 + o * HSZ + e];
  }
  if (STEP0) {
    int bos = P.bosp[0];
    for (int idx = tid; idx < BEAM * TMAX; idx += NTHR) P.bt[idx] = bos;  // buffer 0
  } else {
    const int* src = P.bt + (ti & 1) * (BEAM * TMAX);
    int* dst = P.bt + ((ti + 1) & 1) * (BEAM * TMAX);
    for (int idx = tid; idx < BEAM * TMAX; idx += NTHR) {
      int k = idx / TMAX, jj = idx % TMAX, o = sOrig[k];
      dst[idx] = (jj == ti + 1) ? sTokOld[o] : src[o * TMAX + jj];
    }
  }
  for (int idx = tid; idx < BEAM * HSZ; idx += NTHR) {
    int k = idx >> 9, e = idx & 511;
    P.x_dec[idx] = P.emb_dec[(size_t)sTokNew[k] * HSZ + e];
  }
  if (!STEP0 && ti == TMAX - 2) {
    __syncthreads();
    const int* dst = P.bt + ((ti + 1) & 1) * (BEAM * TMAX);
    for (int jj = tid; jj < TMAX; jj += NTHR) P.outp[jj] = dst[sKstar * TMAX + jj];
  }
}

template <int B, int STEP0>
__device__ void dstep(const Ptrs& P, int blk, int tid, int& nb, int ti) {
  phase_dcell<B>(P.Wih_dec, P.Whh_dec, P.b_dec, P.x_dec, P.hd, P.cd, P.hdn, P.cdn, blk, tid);
  gbar(P, blk, tid, ++nb);
  phase_dcell<B>(P.Wih_dec + LOFF, P.Whh_dec + LOFF, P.b_dec + H4,
                 P.hdn, P.hd + 1536, P.cd + 1536, P.hdn + 1536, P.cdn + 1536, blk, tid);
  gbar(P, blk, tid, ++nb);
  phase_attfeat<B>(P, blk, tid);
  gbar(P, blk, tid, ++nb);
  phase_logits<B>(P, blk, tid);
  // fused barrier: block0's collect == "all partials ready"; merge runs inside
  ++nb;
  bar_arrive(P.flags, blk, tid, nb);
  if (blk == 0) {
    bar_collect(P.flags, tid, nb);
    merge_body<B, STEP0>(P, tid, ti);
    __syncthreads();
    bar_release(P.go, tid, nb);
  } else {
    bar_waitgo(P.go, blk, tid, nb);
  }
}

__global__ void __launch_bounds__(NTHR, 1) mega(Ptrs P) {
  int blk = blockIdx.x, tid = threadIdx.x;
  int nb = 0;

  phase_xw1(P, blk, tid);
  gbar(P, blk, tid, ++nb);
  for (int s = 0; s <= SEQ; ++s) {
    phase_encslot(P, blk, tid, s);
    ++nb;
    bar_arrive(P.flags, blk, tid, nb);
    if (blk == 0) {
      bar_collect(P.flags, tid, nb);
      if (s == SEQ) { dinit_body(P, tid); __syncthreads(); }
      bar_release(P.go, tid, nb);
    } else {
      bar_waitgo(P.go, blk, tid, nb);
    }
  }

  for (int step = 0; step < TMAX; ++step) {
    if (step == 0) dstep<1, 1>(P, blk, tid, nb, -1);
    else           dstep<3, 0>(P, blk, tid, nb, step - 1);
  }
}

extern "C" void kernel_launch(void* const* d_in, const int* in_sizes, int n_in,
                              void* d_out, int out_size, void* d_ws, size_t ws_size,
                              hipStream_t stream) {
  Ptrs P;
  P.seq     = (const int*)d_in[0];
  P.emb_enc = (const float*)d_in[1];
  P.Wih_enc = (const float*)d_in[2];
  P.Whh_enc = (const float*)d_in[3];
  P.b_enc   = (const float*)d_in[4];
  P.emb_dec = (const float*)d_in[5];
  P.Wih_dec = (const float*)d_in[6];
  P.Whh_dec = (const float*)d_in[7];
  P.b_dec   = (const float*)d_in[8];
  P.W_c     = (const float*)d_in[9];
  P.W_out   = (const float*)d_in[10];
  P.b_out   = (const float*)d_in[11];
  P.bosp    = (const int*)d_in[14];

  // barrier region: 256 flag lines (64B) + 16 go lines (64B), zeroed every call
  P.flags = (int*)d_ws;                    // 256*16 ints = 16 KB
  P.go    = (int*)d_ws + NBLK * FLS;       // 16*16 ints = 1 KB

  float* w = (float*)d_ws + NBLK * FLS + 16 * FLS;
  P.xp1     = w; w += SEQ * H4;
  P.h1a     = w; w += (SEQ + 1) * HSZ;
  P.c1a     = w; w += (SEQ + 1) * HSZ;
  P.h2a     = w; w += (SEQ + 1) * HSZ;
  P.c2a     = w; w += (SEQ + 1) * HSZ;
  P.hd      = w; w += 2 * BEAM * HSZ;
  P.cd      = w; w += 2 * BEAM * HSZ;
  P.hdn     = w; w += 2 * BEAM * HSZ;
  P.cdn     = w; w += 2 * BEAM * HSZ;
  P.x_dec   = w; w += BEAM * HSZ;
  P.feat    = w; w += BEAM * HSZ;
  P.pm      = w; w += NBLK * 3;
  P.ps      = w; w += NBLK * 3;
  P.pv      = w; w += NBLK * 3 * 3;
  P.scores  = w; w += 4;
  P.pi      = (int*)w; w += NBLK * 3 * 3;
  P.tokens  = (int*)w; w += 4;
  P.bt      = (int*)w; w += 2 * BEAM * TMAX + 4;
  P.outp    = (int*)d_out;

  hipMemsetAsync(d_ws, 0, (NBLK + 16) * FLS * sizeof(int), stream);
  mega<<<dim3(NBLK), dim3(NTHR), 0, stream>>>(P);
}

// Round 5
// 6077.520 us; speedup vs baseline: 1.2172x; 1.0785x over previous
//
#include <hip/hip_runtime.h>
#include <math.h>

// Problem constants (fixed by the reference module)
#define HSZ   512
#define H4    2048
#define SEQ   64
#define VOC   32000
#define BEAM  3
#define TMAX  50
#define NBLK  256
#define NTHR  256
#define FLS   16        // flag line stride in ints (64 B)

#define LOFF  ((size_t)H4 * HSZ)   // per-layer weight stride

__device__ __forceinline__ float wsum(float v) {
#pragma unroll
  for (int off = 32; off; off >>= 1) v += __shfl_xor(v, off, 64);
  return v;
}
__device__ __forceinline__ float dot4(float4 a, float4 b) {
  return a.x * b.x + a.y * b.y + a.z * b.z + a.w * b.w;
}
__device__ __forceinline__ float sigf(float x) { return 1.f / (1.f + expf(-x)); }

__device__ __forceinline__ bool better(float v1, int i1, float v2, int i2) {
  return (v1 > v2) || (v1 == v2 && i1 < i2);  // jax.lax.top_k order: value desc, index asc
}
__device__ __forceinline__ void ins3(float* v, int* idx, float nv, int ni) {
  if (better(nv, ni, v[2], idx[2])) {
    if (better(nv, ni, v[1], idx[1])) {
      v[2] = v[1]; idx[2] = idx[1];
      if (better(nv, ni, v[0], idx[0])) { v[1] = v[0]; idx[1] = idx[0]; v[0] = nv; idx[0] = ni; }
      else { v[1] = nv; idx[1] = ni; }
    } else { v[2] = nv; idx[2] = ni; }
  }
}

// ---- coherent (L2-bypassing, non-invalidating) accessors for cross-block state ----
__device__ __forceinline__ float agld(const float* p) {
  return __hip_atomic_load(p, __ATOMIC_RELAXED, __HIP_MEMORY_SCOPE_AGENT);
}
__device__ __forceinline__ void agst(float* p, float v) {
  __hip_atomic_store(p, v, __ATOMIC_RELAXED, __HIP_MEMORY_SCOPE_AGENT);
}
__device__ __forceinline__ int agldi(const int* p) {
  return __hip_atomic_load(p, __ATOMIC_RELAXED, __HIP_MEMORY_SCOPE_AGENT);
}
__device__ __forceinline__ void agsti(int* p, int v) {
  __hip_atomic_store(p, v, __ATOMIC_RELAXED, __HIP_MEMORY_SCOPE_AGENT);
}

// ---- relaxed software grid barrier (no acquire/release => no L2 inv/wb) ----
// __syncthreads drains vmcnt => agent stores are at the coherence point before the
// flag store is issued. Readers use relaxed agent loads for shared data, so no
// acquire fence is needed.
__device__ __forceinline__ void bar_arrive(int* flags, int blk, int tid, int ep) {
  __syncthreads();
  if (tid == 0) {
    asm volatile("s_waitcnt vmcnt(0)" ::: "memory");
    agsti(&flags[blk * FLS], ep);
  }
}
__device__ __forceinline__ void bar_collect(int* flags, int tid, int ep) {
  long it = 0;
  while (agldi(&flags[tid * FLS]) < ep && it < 200000000L) ++it;  // bailout beats a hang
  asm volatile("" ::: "memory");
  __syncthreads();
}
__device__ __forceinline__ void bar_release(int* go, int tid, int ep) {
  if (tid < 16) agsti(&go[tid * FLS], ep);
}
__device__ __forceinline__ void bar_waitgo(int* go, int blk, int tid, int ep) {
  if (tid == 0) {
    long it = 0;
    while (agldi(&go[(blk & 15) * FLS]) < ep && it < 200000000L) {
      __builtin_amdgcn_s_sleep(1); ++it;
    }
  }
  asm volatile("" ::: "memory");
  __syncthreads();
}

struct Ptrs {
  const int*   seq;
  const float* emb_enc; const float* Wih_enc; const float* Whh_enc; const float* b_enc;
  const float* emb_dec; const float* Wih_dec; const float* Whh_dec; const float* b_dec;
  const float* W_c; const float* W_out; const float* b_out;
  const int*   bosp;
  int* flags; int* go;
  float* xp1;
  float* h1a; float* c1a; float* h2a; float* c2a;
  float* hd; float* cd; float* hdn; float* cdn;
  float* x_dec; float* feat;
  float* pm; float* ps; float* pv; int* pi;
  float* scores; int* tokens; int* bt;
  int* outp;
};

__device__ __forceinline__ void gbar(const Ptrs& P, int blk, int tid, int ep) {
  bar_arrive(P.flags, blk, tid, ep);
  if (blk == 0) {
    bar_collect(P.flags, tid, ep);
    bar_release(P.go, tid, ep);
  } else {
    bar_waitgo(P.go, blk, tid, ep);
  }
}

// ---------------- encoder phases ----------------

// xp1[t][r] = b_enc[r] + dot(Wih_enc[r], emb_enc[seq[t]])
__device__ void phase_xw1(const Ptrs& P, int blk, int tid) {
  int t  = tid & 63;
  int rl = tid >> 6;
  int tok = P.seq[t];
  const float* xr = P.emb_enc + (size_t)tok * HSZ;
#pragma unroll
  for (int rr = 0; rr < 2; ++rr) {
    int r = blk * 8 + rl * 2 + rr;
    const float* wr = P.Wih_enc + (size_t)r * HSZ;
    float acc = 0.f;
    for (int e = 0; e < HSZ; e += 4) {
      float4 wv = *(const float4*)(wr + e);
      float4 xv = *(const float4*)(xr + e);
      acc += dot4(wv, xv);
    }
    agst(&P.xp1[t * H4 + r], acc + P.b_enc[r]);
  }
}

// One wavefront slot: layer1 cell t=s (blocks 0..127), layer2 cell t=s-1 (blocks 128..255).
// State rows staged into LDS via coherent loads; weights stay plain (L2-warm).
__device__ void phase_encslot(const Ptrs& P, float* sm, int blk, int tid, int s) {
  int wave = tid >> 6, lane = tid & 63;
  bool l2  = blk >= 128;
  int t    = l2 ? s - 1 : s;
  if (t < 0 || t >= SEQ) return;
  int j = (blk - (l2 ? 128 : 0)) * 4 + wave;  // 0..511
  float* rowX = sm;         // 512 floats
  float* rowH = sm + 512;   // 512 floats (l2 only)
  if (!l2) {
    if (t > 0) { for (int i = tid; i < HSZ; i += NTHR) rowX[i] = agld(&P.h1a[t * HSZ + i]); }
    else       { for (int i = tid; i < HSZ; i += NTHR) rowX[i] = 0.f; }
    __syncthreads();
    float4 h0 = ((const float4*)rowX)[lane], h1v = ((const float4*)rowX)[lane + 64];
    float zs[4];
#pragma unroll
    for (int g = 0; g < 4; ++g) {
      int row = j + (g << 9);
      const float4* wr = (const float4*)(P.Whh_enc + (size_t)row * HSZ);
      zs[g] = wsum(dot4(wr[lane], h0) + dot4(wr[lane + 64], h1v));
    }
    if (lane == 0) {
      float z0 = zs[0] + agld(&P.xp1[t * H4 + j]);
      float z1 = zs[1] + agld(&P.xp1[t * H4 + j + 512]);
      float z2 = zs[2] + agld(&P.xp1[t * H4 + j + 1024]);
      float z3 = zs[3] + agld(&P.xp1[t * H4 + j + 1536]);
      float cp = (t > 0) ? agld(&P.c1a[t * HSZ + j]) : 0.f;
      float c = sigf(z1) * cp + sigf(z0) * tanhf(z2);
      agst(&P.c1a[(t + 1) * HSZ + j], c);
      agst(&P.h1a[(t + 1) * HSZ + j], sigf(z3) * tanhf(c));
    }
  } else {
    for (int i = tid; i < HSZ; i += NTHR) rowX[i] = agld(&P.h1a[(t + 1) * HSZ + i]);
    if (t > 0) { for (int i = tid; i < HSZ; i += NTHR) rowH[i] = agld(&P.h2a[t * HSZ + i]); }
    else       { for (int i = tid; i < HSZ; i += NTHR) rowH[i] = 0.f; }
    __syncthreads();
    float4 x0 = ((const float4*)rowX)[lane], x1 = ((const float4*)rowX)[lane + 64];
    float4 h0 = ((const float4*)rowH)[lane], h1v = ((const float4*)rowH)[lane + 64];
    float zs[4];
#pragma unroll
    for (int g = 0; g < 4; ++g) {
      int row = j + (g << 9);
      const float4* wi = (const float4*)(P.Wih_enc + LOFF + (size_t)row * HSZ);
      const float4* wh = (const float4*)(P.Whh_enc + LOFF + (size_t)row * HSZ);
      zs[g] = wsum(dot4(wi[lane], x0) + dot4(wi[lane + 64], x1) +
                   dot4(wh[lane], h0) + dot4(wh[lane + 64], h1v));
    }
    if (lane == 0) {
      float z0 = zs[0] + P.b_enc[H4 + j];
      float z1 = zs[1] + P.b_enc[H4 + j + 512];
      float z2 = zs[2] + P.b_enc[H4 + j + 1024];
      float z3 = zs[3] + P.b_enc[H4 + j + 1536];
      float cp = (t > 0) ? agld(&P.c2a[t * HSZ + j]) : 0.f;
      float c = sigf(z1) * cp + sigf(z0) * tanhf(z2);
      agst(&P.c2a[(t + 1) * HSZ + j], c);
      agst(&P.h2a[(t + 1) * HSZ + j], sigf(z3) * tanhf(c));
    }
  }
}

// run by block 0 inside the last encoder slot's barrier
__device__ void dinit_body(const Ptrs& P, int tid) {
  int bos = P.bosp[0];
  for (int e = tid; e < HSZ; e += NTHR) {
    agst(&P.hd[e],        agld(&P.h1a[SEQ * HSZ + e]));
    agst(&P.cd[e],        agld(&P.c1a[SEQ * HSZ + e]));
    agst(&P.hd[1536 + e], agld(&P.h2a[SEQ * HSZ + e]));
    agst(&P.cd[1536 + e], agld(&P.c2a[SEQ * HSZ + e]));
    agst(&P.x_dec[e],     P.emb_dec[(size_t)bos * HSZ + e]);
  }
}

// ---------------- decoder phases ----------------

template <int B>
__device__ void phase_dcell(const Ptrs& P, float* sm,
                            const float* __restrict__ Wih, const float* __restrict__ Whh,
                            const float* __restrict__ bias, const float* x,
                            const float* hin, const float* cin,
                            float* hout, float* cout, int blk, int tid) {
  if (blk >= 128) return;
  float* xl = sm;
  float* hl = sm + B * HSZ;
  float* cl = sm + 2 * B * HSZ;
  for (int i = tid; i < B * HSZ; i += NTHR) {
    xl[i] = agld(&x[i]); hl[i] = agld(&hin[i]); cl[i] = agld(&cin[i]);
  }
  __syncthreads();
  int wave = tid >> 6, lane = tid & 63;
  int j = blk * 4 + wave;
  float4 xv[B][2], hv[B][2];
#pragma unroll
  for (int b = 0; b < B; ++b) {
    xv[b][0] = ((const float4*)(xl + b * HSZ))[lane];
    xv[b][1] = ((const float4*)(xl + b * HSZ))[lane + 64];
    hv[b][0] = ((const float4*)(hl + b * HSZ))[lane];
    hv[b][1] = ((const float4*)(hl + b * HSZ))[lane + 64];
  }
  float z[4][B];
#pragma unroll
  for (int g = 0; g < 4; ++g) {
    int row = j + (g << 9);
    const float4* wi = (const float4*)(Wih + (size_t)row * HSZ);
    const float4* wh = (const float4*)(Whh + (size_t)row * HSZ);
    float4 wi0 = wi[lane], wi1 = wi[lane + 64], wh0 = wh[lane], wh1 = wh[lane + 64];
    float bb = bias[row];
#pragma unroll
    for (int b = 0; b < B; ++b) {
      float acc = dot4(wi0, xv[b][0]) + dot4(wi1, xv[b][1]) +
                  dot4(wh0, hv[b][0]) + dot4(wh1, hv[b][1]);
      z[g][b] = wsum(acc) + bb;
    }
  }
  if (lane == 0) {
#pragma unroll
    for (int b = 0; b < B; ++b) {
      float c = sigf(z[1][b]) * cl[b * HSZ + j] + sigf(z[0][b]) * tanhf(z[2][b]);
      agst(&cout[b * HSZ + j], c);
      agst(&hout[b * HSZ + j], sigf(z[3][b]) * tanhf(c));
    }
  }
}

// attention (redundant per block) + context + feat; blocks 0..127
// h2a is immutable after the encoder -> plain cached reads (L2-warm).
template <int B>
__device__ void phase_attfeat(const Ptrs& P, float* sm, int blk, int tid) {
  if (blk >= 128) return;  // block-uniform
  float* xs  = sm;            // B*HSZ
  float* at  = sm + 1536;     // B*SEQ
  float* xcs = sm + 1728;     // B*1024
  for (int i = tid; i < B * HSZ; i += NTHR) xs[i] = agld(&P.hdn[1536 + i]);
  __syncthreads();
  for (int i = tid; i < B * SEQ; i += NTHR) {
    int b = i >> 6, s2 = i & 63;
    const float* er = P.h2a + (s2 + 1) * HSZ;
    const float* xb = xs + b * HSZ;
    float acc = 0.f;
    for (int e = 0; e < HSZ; e += 4) {
      float4 ev = *(const float4*)(er + e);
      acc += ev.x * xb[e] + ev.y * xb[e + 1] + ev.z * xb[e + 2] + ev.w * xb[e + 3];
    }
    at[i] = acc;
  }
  __syncthreads();
  if (tid < B) {
    float m = -INFINITY;
    for (int s2 = 0; s2 < SEQ; ++s2) m = fmaxf(m, at[tid * SEQ + s2]);
    float s = 0.f;
    for (int s2 = 0; s2 < SEQ; ++s2) { float e = expf(at[tid * SEQ + s2] - m); at[tid * SEQ + s2] = e; s += e; }
    float inv = 1.f / s;
    for (int s2 = 0; s2 < SEQ; ++s2) at[tid * SEQ + s2] *= inv;
  }
  __syncthreads();
  if (tid < 128) {
    int h4 = tid * 4;
    float4 acc[B];
#pragma unroll
    for (int b = 0; b < B; ++b) acc[b] = make_float4(0.f, 0.f, 0.f, 0.f);
    for (int s2 = 0; s2 < SEQ; ++s2) {
      float4 ev = *(const float4*)(P.h2a + (s2 + 1) * HSZ + h4);
#pragma unroll
      for (int b = 0; b < B; ++b) {
        float a = at[b * SEQ + s2];
        acc[b].x += a * ev.x; acc[b].y += a * ev.y; acc[b].z += a * ev.z; acc[b].w += a * ev.w;
      }
    }
#pragma unroll
    for (int b = 0; b < B; ++b) *(float4*)(xcs + b * 1024 + 512 + h4) = acc[b];
  }
  for (int i = tid; i < B * HSZ; i += NTHR) {
    int b = i >> 9, hcol = i & 511;
    xcs[b * 1024 + hcol] = xs[b * HSZ + hcol];
  }
  __syncthreads();
  int wave = tid >> 6, lane = tid & 63;
  int j = blk * 4 + wave;
  const float4* w = (const float4*)(P.W_c + (size_t)j * 1024);
  float4 w0 = w[lane], w1 = w[lane + 64], w2 = w[lane + 128], w3 = w[lane + 192];
#pragma unroll
  for (int b = 0; b < B; ++b) {
    const float4* xb = (const float4*)(xcs + b * 1024);
    float acc = dot4(w0, xb[lane]) + dot4(w1, xb[lane + 64]) +
                dot4(w2, xb[lane + 128]) + dot4(w3, xb[lane + 192]);
    acc = wsum(acc);
    if (lane == 0) agst(&P.feat[b * HSZ + j], tanhf(acc));
  }
}

// logits + streaming (max, sumexp, top3) per beam per block; all 256 blocks
template <int B>
__device__ void phase_logits(const Ptrs& P, float* sm, int blk, int tid) {
  float* fst = sm;  // B*HSZ
  for (int i = tid; i < B * HSZ; i += NTHR) fst[i] = agld(&P.feat[i]);
  __syncthreads();
  int wave = tid >> 6, lane = tid & 63;
  int gid  = blk * 4 + wave;  // 0..1023
  float4 f0[B], f1[B];
#pragma unroll
  for (int b = 0; b < B; ++b) {
    f0[b] = ((const float4*)(fst + b * HSZ))[lane];
    f1[b] = ((const float4*)(fst + b * HSZ))[lane + 64];
  }
  float m[B], ss[B], tv[B][3];
  int tix[B][3];
#pragma unroll
  for (int b = 0; b < B; ++b) {
    m[b] = -INFINITY; ss[b] = 0.f;
#pragma unroll
    for (int k = 0; k < 3; ++k) { tv[b][k] = -INFINITY; tix[b][k] = 0x7fffffff; }
  }
  // 1-deep row prefetch: issue next row's loads before this row's reduce
  int v = gid;
  const float4* wr = (const float4*)(P.W_out + (size_t)v * HSZ);
  float4 w0 = wr[lane], w1 = wr[lane + 64];
  float bo = P.b_out[v];
  while (v < VOC) {
    int vn = v + 1024;
    float4 n0 = make_float4(0.f, 0.f, 0.f, 0.f), n1 = n0;
    float bn = 0.f;
    if (vn < VOC) {
      const float4* wrn = (const float4*)(P.W_out + (size_t)vn * HSZ);
      n0 = wrn[lane]; n1 = wrn[lane + 64]; bn = P.b_out[vn];
    }
#pragma unroll
    for (int b = 0; b < B; ++b) {
      float acc = wsum(dot4(w0, f0[b]) + dot4(w1, f1[b])) + bo;
      float mo = m[b], mn = fmaxf(mo, acc);
      ss[b] = ss[b] * expf(mo - mn) + expf(acc - mn);
      m[b]  = mn;
      ins3(tv[b], tix[b], acc, v);
    }
    w0 = n0; w1 = n1; bo = bn; v = vn;
  }
  __shared__ float lm[4][3], lss[4][3], lv[4][3][3];
  __shared__ int li[4][3][3];
  if (lane == 0) {
#pragma unroll
    for (int b = 0; b < B; ++b) {
      lm[wave][b] = m[b]; lss[wave][b] = ss[b];
#pragma unroll
      for (int k = 0; k < 3; ++k) { lv[wave][b][k] = tv[b][k]; li[wave][b][k] = tix[b][k]; }
    }
  }
  __syncthreads();
  if (tid < B) {
    int b = tid;
    float M = fmaxf(fmaxf(lm[0][b], lm[1][b]), fmaxf(lm[2][b], lm[3][b]));
    float S = 0.f;
#pragma unroll
    for (int w2 = 0; w2 < 4; ++w2) S += lss[w2][b] * expf(lm[w2][b] - M);
    float bv[3] = {-INFINITY, -INFINITY, -INFINITY};
    int bi3[3]  = {0x7fffffff, 0x7fffffff, 0x7fffffff};
#pragma unroll
    for (int w2 = 0; w2 < 4; ++w2)
#pragma unroll
      for (int k = 0; k < 3; ++k) ins3(bv, bi3, lv[w2][b][k], li[w2][b][k]);
    int o = blk * 3 + b;
    agst(&P.pm[o], M); agst(&P.ps[o], S);
#pragma unroll
    for (int k = 0; k < 3; ++k) { agst(&P.pv[o * 3 + k], bv[k]); agsti(&P.pi[o * 3 + k], bi3[k]); }
  }
}

// final merge + beam bookkeeping; run by block 0's 256 threads inside the logits barrier
template <int B, int STEP0>
__device__ void merge_body(const Ptrs& P, int tid, int ti) {
  __shared__ float sM[3], sS[3], sV[3][3], sScore[3];
  __shared__ int sI[3][3], sOrig[3], sTokNew[3], sTokOld[3], sKstar;
  int wave = tid >> 6, lane = tid & 63;
  if (wave < B) {
    int b = wave;
    float lm4[4], ls4[4];
    float M = -INFINITY;
#pragma unroll
    for (int q = 0; q < 4; ++q) {
      int blk2 = lane + q * 64;
      lm4[q] = agld(&P.pm[blk2 * 3 + b]); ls4[q] = agld(&P.ps[blk2 * 3 + b]);
      M = fmaxf(M, lm4[q]);
    }
#pragma unroll
    for (int off = 32; off; off >>= 1) M = fmaxf(M, __shfl_xor(M, off, 64));
    float S = 0.f;
#pragma unroll
    for (int q = 0; q < 4; ++q) S += ls4[q] * expf(lm4[q] - M);
    S = wsum(S);
    float bv[3] = {-INFINITY, -INFINITY, -INFINITY};
    int bi3[3]  = {0x7fffffff, 0x7fffffff, 0x7fffffff};
#pragma unroll
    for (int q = 0; q < 4; ++q) {
      int blk2 = lane + q * 64;
#pragma unroll
      for (int k = 0; k < 3; ++k)
        ins3(bv, bi3, agld(&P.pv[(blk2 * 3 + b) * 3 + k]), agldi(&P.pi[(blk2 * 3 + b) * 3 + k]));
    }
#pragma unroll
    for (int off = 32; off; off >>= 1) {
      float ov[3]; int oi[3];
#pragma unroll
      for (int k = 0; k < 3; ++k) { ov[k] = __shfl_xor(bv[k], off, 64); oi[k] = __shfl_xor(bi3[k], off, 64); }
#pragma unroll
      for (int k = 0; k < 3; ++k) ins3(bv, bi3, ov[k], oi[k]);
    }
    if (lane == 0) {
      sM[b] = M; sS[b] = S;
#pragma unroll
      for (int k = 0; k < 3; ++k) { sV[b][k] = bv[k]; sI[b][k] = bi3[k]; }
    }
  }
  __syncthreads();
  if (tid == 0) {
    if (STEP0) {
      float off0 = -sM[0] - logf(sS[0]);
      for (int k = 0; k < 3; ++k) {
        sScore[k] = sV[0][k] + off0;
        sTokNew[k] = sI[0][k]; sOrig[k] = 0; sTokOld[k] = 0;
        P.scores[k] = sScore[k]; P.tokens[k] = sTokNew[k];
      }
    } else {
      float osc[3]; int otk[3];
      for (int b = 0; b < 3; ++b) { osc[b] = P.scores[b]; otk[b] = P.tokens[b]; sTokOld[b] = otk[b]; }
      float cum[9];
      for (int b = 0; b < 3; ++b) {
        float o = osc[b] - sM[b] - logf(sS[b]);
        for (int k = 0; k < 3; ++k) cum[b * 3 + k] = sV[b][k] + o;
      }
      bool used[9] = {false, false, false, false, false, false, false, false, false};
      for (int k = 0; k < 3; ++k) {
        int bf = 0; float bb = -INFINITY;
        for (int f = 0; f < 9; ++f)
          if (!used[f] && cum[f] > bb) { bb = cum[f]; bf = f; }  // strict > keeps lowest flat idx
        used[bf] = true;
        sScore[k] = bb;
        int ob = bf / 3;
        sOrig[k] = ob;
        sTokNew[k] = sI[ob][bf - ob * 3];
      }
      for (int k = 0; k < 3; ++k) { P.scores[k] = sScore[k]; P.tokens[k] = sTokNew[k]; }
    }
    float bb = -INFINITY; int kk = 0;
    for (int k = 0; k < 3; ++k) if (sScore[k] > bb) { bb = sScore[k]; kk = k; }
    sKstar = kk;
  }
  __syncthreads();
  for (int idx = tid; idx < 2 * 3 * HSZ; idx += NTHR) {
    int l = idx / 1536, rem = idx % 1536, k = rem / HSZ, e = rem & 511;
    int o = STEP0 ? 0 : sOrig[k];
    agst(&P.hd[l * 1536 + k * HSZ + e], agld(&P.hdn[l * 1536 + o * HSZ + e]));
    agst(&P.cd[l * 1536 + k * HSZ + e], agld(&P.cdn[l * 1536 + o * HSZ + e]));
  }
  if (STEP0) {
    int bos = P.bosp[0];
    for (int idx = tid; idx < BEAM * TMAX; idx += NTHR) P.bt[idx] = bos;  // buffer 0
  } else {
    const int* src = P.bt + (ti & 1) * (BEAM * TMAX);
    int* dst = P.bt + ((ti + 1) & 1) * (BEAM * TMAX);
    for (int idx = tid; idx < BEAM * TMAX; idx += NTHR) {
      int k = idx / TMAX, jj = idx % TMAX, o = sOrig[k];
      dst[idx] = (jj == ti + 1) ? sTokOld[o] : src[o * TMAX + jj];
    }
  }
  for (int idx = tid; idx < BEAM * HSZ; idx += NTHR) {
    int k = idx >> 9, e = idx & 511;
    agst(&P.x_dec[idx], P.emb_dec[(size_t)sTokNew[k] * HSZ + e]);
  }
  if (!STEP0 && ti == TMAX - 2) {
    __syncthreads();
    const int* dst = P.bt + ((ti + 1) & 1) * (BEAM * TMAX);
    for (int jj = tid; jj < TMAX; jj += NTHR) P.outp[jj] = dst[sKstar * TMAX + jj];
  }
}

template <int B, int STEP0>
__device__ void dstep(const Ptrs& P, float* sm, int blk, int tid, int& nb, int ti) {
  phase_dcell<B>(P, sm, P.Wih_dec, P.Whh_dec, P.b_dec, P.x_dec, P.hd, P.cd, P.hdn, P.cdn, blk, tid);
  gbar(P, blk, tid, ++nb);
  phase_dcell<B>(P, sm, P.Wih_dec + LOFF, P.Whh_dec + LOFF, P.b_dec + H4,
                 P.hdn, P.hd + 1536, P.cd + 1536, P.hdn + 1536, P.cdn + 1536, blk, tid);
  gbar(P, blk, tid, ++nb);
  phase_attfeat<B>(P, sm, blk, tid);
  gbar(P, blk, tid, ++nb);
  phase_logits<B>(P, sm, blk, tid);
  // fused barrier: block0's collect == "all partials ready"; merge runs inside
  ++nb;
  bar_arrive(P.flags, blk, tid, nb);
  if (blk == 0) {
    bar_collect(P.flags, tid, nb);
    merge_body<B, STEP0>(P, tid, ti);
    __syncthreads();
    bar_release(P.go, tid, nb);
  } else {
    bar_waitgo(P.go, blk, tid, nb);
  }
}

__global__ void __launch_bounds__(NTHR, 1) mega(Ptrs P) {
  __shared__ float sm[4800];  // shared arena, reused by all phases
  int blk = blockIdx.x, tid = threadIdx.x;
  int nb = 0;

  phase_xw1(P, blk, tid);
  gbar(P, blk, tid, ++nb);
  for (int s = 0; s <= SEQ; ++s) {
    phase_encslot(P, sm, blk, tid, s);
    ++nb;
    bar_arrive(P.flags, blk, tid, nb);
    if (blk == 0) {
      bar_collect(P.flags, tid, nb);
      if (s == SEQ) { dinit_body(P, tid); __syncthreads(); }
      bar_release(P.go, tid, nb);
    } else {
      bar_waitgo(P.go, blk, tid, nb);
    }
  }

  for (int step = 0; step < TMAX; ++step) {
    if (step == 0) dstep<1, 1>(P, sm, blk, tid, nb, -1);
    else           dstep<3, 0>(P, sm, blk, tid, nb, step - 1);
  }
}

extern "C" void kernel_launch(void* const* d_in, const int* in_sizes, int n_in,
                              void* d_out, int out_size, void* d_ws, size_t ws_size,
                              hipStream_t stream) {
  Ptrs P;
  P.seq     = (const int*)d_in[0];
  P.emb_enc = (const float*)d_in[1];
  P.Wih_enc = (const float*)d_in[2];
  P.Whh_enc = (const float*)d_in[3];
  P.b_enc   = (const float*)d_in[4];
  P.emb_dec = (const float*)d_in[5];
  P.Wih_dec = (const float*)d_in[6];
  P.Whh_dec = (const float*)d_in[7];
  P.b_dec   = (const float*)d_in[8];
  P.W_c     = (const float*)d_in[9];
  P.W_out   = (const float*)d_in[10];
  P.b_out   = (const float*)d_in[11];
  P.bosp    = (const int*)d_in[14];

  // barrier region: 256 flag lines + 16 go lines (64 B each), zeroed every call
  P.flags = (int*)d_ws;
  P.go    = (int*)d_ws + NBLK * FLS;

  float* w = (float*)d_ws + (NBLK + 16) * FLS;
  P.xp1     = w; w += SEQ * H4;
  P.h1a     = w; w += (SEQ + 1) * HSZ;
  P.c1a     = w; w += (SEQ + 1) * HSZ;
  P.h2a     = w; w += (SEQ + 1) * HSZ;
  P.c2a     = w; w += (SEQ + 1) * HSZ;
  P.hd      = w; w += 2 * BEAM * HSZ;
  P.cd      = w; w += 2 * BEAM * HSZ;
  P.hdn     = w; w += 2 * BEAM * HSZ;
  P.cdn     = w; w += 2 * BEAM * HSZ;
  P.x_dec   = w; w += BEAM * HSZ;
  P.feat    = w; w += BEAM * HSZ;
  P.pm      = w; w += NBLK * 3;
  P.ps      = w; w += NBLK * 3;
  P.pv      = w; w += NBLK * 3 * 3;
  P.scores  = w; w += 4;
  P.pi      = (int*)w; w += NBLK * 3 * 3;
  P.tokens  = (int*)w; w += 4;
  P.bt      = (int*)w; w += 2 * BEAM * TMAX + 4;
  P.outp    = (int*)d_out;

  hipMemsetAsync(d_ws, 0, (NBLK + 16) * FLS * sizeof(int), stream);
  mega<<<dim3(NBLK), dim3(NTHR), 0, stream>>>(P);
}

// Round 6
// 5988.826 us; speedup vs baseline: 1.2352x; 1.0148x over previous
//
#include <hip/hip_runtime.h>
#include <math.h>

// Problem constants (fixed by the reference module)
#define HSZ   512
#define H4    2048
#define SEQ   64
#define VOC   32000
#define BEAM  3
#define TMAX  50
#define NBLK  256
#define NTHR  256
#define FLS   16        // flag line stride in ints (64 B)

#define LOFF  ((size_t)H4 * HSZ)   // per-layer weight stride

__device__ __forceinline__ float wsum(float v) {
#pragma unroll
  for (int off = 32; off; off >>= 1) v += __shfl_xor(v, off, 64);
  return v;
}
__device__ __forceinline__ float dot4(float4 a, float4 b) {
  return a.x * b.x + a.y * b.y + a.z * b.z + a.w * b.w;
}
__device__ __forceinline__ float sigf(float x) { return 1.f / (1.f + expf(-x)); }

__device__ __forceinline__ bool better(float v1, int i1, float v2, int i2) {
  return (v1 > v2) || (v1 == v2 && i1 < i2);  // jax.lax.top_k order: value desc, index asc
}
__device__ __forceinline__ void ins3(float* v, int* idx, float nv, int ni) {
  if (better(nv, ni, v[2], idx[2])) {
    if (better(nv, ni, v[1], idx[1])) {
      v[2] = v[1]; idx[2] = idx[1];
      if (better(nv, ni, v[0], idx[0])) { v[1] = v[0]; idx[1] = idx[0]; v[0] = nv; idx[0] = ni; }
      else { v[1] = nv; idx[1] = ni; }
    } else { v[2] = nv; idx[2] = ni; }
  }
}

// ---- coherent accessors for cross-block state (relaxed, agent scope) ----
__device__ __forceinline__ float agld(const float* p) {
  return __hip_atomic_load(p, __ATOMIC_RELAXED, __HIP_MEMORY_SCOPE_AGENT);
}
__device__ __forceinline__ void agst(float* p, float v) {
  __hip_atomic_store(p, v, __ATOMIC_RELAXED, __HIP_MEMORY_SCOPE_AGENT);
}
__device__ __forceinline__ int agldi(const int* p) {
  return __hip_atomic_load(p, __ATOMIC_RELAXED, __HIP_MEMORY_SCOPE_AGENT);
}
__device__ __forceinline__ void agsti(int* p, int v) {
  __hip_atomic_store(p, v, __ATOMIC_RELAXED, __HIP_MEMORY_SCOPE_AGENT);
}

// ---- RMW-only grid barrier: every leg executes AT the L3 coherence point ----
// arrive: fetch_max (visible immediately, no store-drain dependence)
// poll:   fetch_add(p, 0) — forced read-at-L3, immune to stale cached copies
__device__ __forceinline__ void rmw_set(int* p, int ep) {
  __hip_atomic_fetch_max(p, ep, __ATOMIC_RELAXED, __HIP_MEMORY_SCOPE_AGENT);
}
__device__ __forceinline__ int rmw_get(int* p) {
  return __hip_atomic_fetch_add(p, 0, __ATOMIC_RELAXED, __HIP_MEMORY_SCOPE_AGENT);
}

__device__ __forceinline__ void bar_arrive(int* flags, int blk, int tid, int ep) {
  __syncthreads();  // each wave drains vmcnt at s_barrier => data stores globally ordered
  if (tid == 0) rmw_set(&flags[blk * FLS], ep);
}
__device__ __forceinline__ void bar_collect(int* flags, int tid, int ep) {
  long it = 0;
  while (rmw_get(&flags[tid * FLS]) < ep && it < 100000000L) ++it;  // bailout beats a hang
  asm volatile("" ::: "memory");
  __syncthreads();
}
__device__ __forceinline__ void bar_release(int* go, int tid, int ep) {
  if (tid < 16) rmw_set(&go[tid * FLS], ep);
}
__device__ __forceinline__ void bar_waitgo(int* go, int blk, int tid, int ep) {
  if (tid == 0) {
    long it = 0;
    while (rmw_get(&go[(blk & 15) * FLS]) < ep && it < 100000000L) {
      __builtin_amdgcn_s_sleep(1); ++it;
    }
  }
  asm volatile("" ::: "memory");
  __syncthreads();
}

struct Ptrs {
  const int*   seq;
  const float* emb_enc; const float* Wih_enc; const float* Whh_enc; const float* b_enc;
  const float* emb_dec; const float* Wih_dec; const float* Whh_dec; const float* b_dec;
  const float* W_c; const float* W_out; const float* b_out;
  const int*   bosp;
  int* flags; int* go;
  float* xp1;
  float* h1a; float* c1a; float* h2a; float* c2a;
  float* hd; float* cd; float* hdn; float* cdn;
  float* x_dec; float* feat;
  float* pm; float* ps; float* pv; int* pi;
  float* scores; int* tokens; int* bt;
  int* outp;
};

__device__ __forceinline__ void gbar(const Ptrs& P, int blk, int tid, int ep) {
  bar_arrive(P.flags, blk, tid, ep);
  if (blk == 0) {
    bar_collect(P.flags, tid, ep);
    bar_release(P.go, tid, ep);
  } else {
    bar_waitgo(P.go, blk, tid, ep);
  }
}

// ---------------- encoder phases ----------------

// xp1[t][r] = b_enc[r] + dot(Wih_enc[r], emb_enc[seq[t]])
__device__ void phase_xw1(const Ptrs& P, int blk, int tid) {
  int t  = tid & 63;
  int rl = tid >> 6;
  int tok = P.seq[t];
  const float* xr = P.emb_enc + (size_t)tok * HSZ;
#pragma unroll
  for (int rr = 0; rr < 2; ++rr) {
    int r = blk * 8 + rl * 2 + rr;
    const float* wr = P.Wih_enc + (size_t)r * HSZ;
    float acc = 0.f;
    for (int e = 0; e < HSZ; e += 4) {
      float4 wv = *(const float4*)(wr + e);
      float4 xv = *(const float4*)(xr + e);
      acc += dot4(wv, xv);
    }
    agst(&P.xp1[t * H4 + r], acc + P.b_enc[r]);
  }
}

// One wavefront slot: layer1 cell t=s (blocks 0..127), layer2 cell t=s-1 (blocks 128..255).
__device__ void phase_encslot(const Ptrs& P, float* sm, int blk, int tid, int s) {
  int wave = tid >> 6, lane = tid & 63;
  bool l2  = blk >= 128;
  int t    = l2 ? s - 1 : s;
  if (t < 0 || t >= SEQ) return;
  int j = (blk - (l2 ? 128 : 0)) * 4 + wave;  // 0..511
  float* rowX = sm;         // 512 floats
  float* rowH = sm + 512;   // 512 floats (l2 only)
  if (!l2) {
    if (t > 0) { for (int i = tid; i < HSZ; i += NTHR) rowX[i] = agld(&P.h1a[t * HSZ + i]); }
    else       { for (int i = tid; i < HSZ; i += NTHR) rowX[i] = 0.f; }
    __syncthreads();
    float4 h0 = ((const float4*)rowX)[lane], h1v = ((const float4*)rowX)[lane + 64];
    float zs[4];
#pragma unroll
    for (int g = 0; g < 4; ++g) {
      int row = j + (g << 9);
      const float4* wr = (const float4*)(P.Whh_enc + (size_t)row * HSZ);
      zs[g] = wsum(dot4(wr[lane], h0) + dot4(wr[lane + 64], h1v));
    }
    if (lane == 0) {
      float z0 = zs[0] + agld(&P.xp1[t * H4 + j]);
      float z1 = zs[1] + agld(&P.xp1[t * H4 + j + 512]);
      float z2 = zs[2] + agld(&P.xp1[t * H4 + j + 1024]);
      float z3 = zs[3] + agld(&P.xp1[t * H4 + j + 1536]);
      float cp = (t > 0) ? agld(&P.c1a[t * HSZ + j]) : 0.f;
      float c = sigf(z1) * cp + sigf(z0) * tanhf(z2);
      agst(&P.c1a[(t + 1) * HSZ + j], c);
      agst(&P.h1a[(t + 1) * HSZ + j], sigf(z3) * tanhf(c));
    }
  } else {
    for (int i = tid; i < HSZ; i += NTHR) rowX[i] = agld(&P.h1a[(t + 1) * HSZ + i]);
    if (t > 0) { for (int i = tid; i < HSZ; i += NTHR) rowH[i] = agld(&P.h2a[t * HSZ + i]); }
    else       { for (int i = tid; i < HSZ; i += NTHR) rowH[i] = 0.f; }
    __syncthreads();
    float4 x0 = ((const float4*)rowX)[lane], x1 = ((const float4*)rowX)[lane + 64];
    float4 h0 = ((const float4*)rowH)[lane], h1v = ((const float4*)rowH)[lane + 64];
    float zs[4];
#pragma unroll
    for (int g = 0; g < 4; ++g) {
      int row = j + (g << 9);
      const float4* wi = (const float4*)(P.Wih_enc + LOFF + (size_t)row * HSZ);
      const float4* wh = (const float4*)(P.Whh_enc + LOFF + (size_t)row * HSZ);
      zs[g] = wsum(dot4(wi[lane], x0) + dot4(wi[lane + 64], x1) +
                   dot4(wh[lane], h0) + dot4(wh[lane + 64], h1v));
    }
    if (lane == 0) {
      float z0 = zs[0] + P.b_enc[H4 + j];
      float z1 = zs[1] + P.b_enc[H4 + j + 512];
      float z2 = zs[2] + P.b_enc[H4 + j + 1024];
      float z3 = zs[3] + P.b_enc[H4 + j + 1536];
      float cp = (t > 0) ? agld(&P.c2a[t * HSZ + j]) : 0.f;
      float c = sigf(z1) * cp + sigf(z0) * tanhf(z2);
      agst(&P.c2a[(t + 1) * HSZ + j], c);
      agst(&P.h2a[(t + 1) * HSZ + j], sigf(z3) * tanhf(c));
    }
  }
}

// run by block 0 inside the last encoder slot's barrier
__device__ void dinit_body(const Ptrs& P, int tid) {
  int bos = P.bosp[0];
  for (int e = tid; e < HSZ; e += NTHR) {
    agst(&P.hd[e],        agld(&P.h1a[SEQ * HSZ + e]));
    agst(&P.cd[e],        agld(&P.c1a[SEQ * HSZ + e]));
    agst(&P.hd[1536 + e], agld(&P.h2a[SEQ * HSZ + e]));
    agst(&P.cd[1536 + e], agld(&P.c2a[SEQ * HSZ + e]));
    agst(&P.x_dec[e],     P.emb_dec[(size_t)bos * HSZ + e]);
  }
}

// ---------------- decoder phases ----------------

template <int B>
__device__ void phase_dcell(const Ptrs& P, float* sm,
                            const float* __restrict__ Wih, const float* __restrict__ Whh,
                            const float* __restrict__ bias, const float* x,
                            const float* hin, const float* cin,
                            float* hout, float* cout, int blk, int tid) {
  if (blk >= 128) return;
  float* xl = sm;
  float* hl = sm + B * HSZ;
  float* cl = sm + 2 * B * HSZ;
  for (int i = tid; i < B * HSZ; i += NTHR) {
    xl[i] = agld(&x[i]); hl[i] = agld(&hin[i]); cl[i] = agld(&cin[i]);
  }
  __syncthreads();
  int wave = tid >> 6, lane = tid & 63;
  int j = blk * 4 + wave;
  float4 xv[B][2], hv[B][2];
#pragma unroll
  for (int b = 0; b < B; ++b) {
    xv[b][0] = ((const float4*)(xl + b * HSZ))[lane];
    xv[b][1] = ((const float4*)(xl + b * HSZ))[lane + 64];
    hv[b][0] = ((const float4*)(hl + b * HSZ))[lane];
    hv[b][1] = ((const float4*)(hl + b * HSZ))[lane + 64];
  }
  float z[4][B];
#pragma unroll
  for (int g = 0; g < 4; ++g) {
    int row = j + (g << 9);
    const float4* wi = (const float4*)(Wih + (size_t)row * HSZ);
    const float4* wh = (const float4*)(Whh + (size_t)row * HSZ);
    float4 wi0 = wi[lane], wi1 = wi[lane + 64], wh0 = wh[lane], wh1 = wh[lane + 64];
    float bb = bias[row];
#pragma unroll
    for (int b = 0; b < B; ++b) {
      float acc = dot4(wi0, xv[b][0]) + dot4(wi1, xv[b][1]) +
                  dot4(wh0, hv[b][0]) + dot4(wh1, hv[b][1]);
      z[g][b] = wsum(acc) + bb;
    }
  }
  if (lane == 0) {
#pragma unroll
    for (int b = 0; b < B; ++b) {
      float c = sigf(z[1][b]) * cl[b * HSZ + j] + sigf(z[0][b]) * tanhf(z[2][b]);
      agst(&cout[b * HSZ + j], c);
      agst(&hout[b * HSZ + j], sigf(z[3][b]) * tanhf(c));
    }
  }
}

// attention (redundant per block) + context + feat; blocks 0..127
// h2a is immutable after the encoder -> plain cached reads (L2-warm).
template <int B>
__device__ void phase_attfeat(const Ptrs& P, float* sm, int blk, int tid) {
  if (blk >= 128) return;  // block-uniform
  float* xs  = sm;            // B*HSZ
  float* at  = sm + 1536;     // B*SEQ
  float* xcs = sm + 1728;     // B*1024
  for (int i = tid; i < B * HSZ; i += NTHR) xs[i] = agld(&P.hdn[1536 + i]);
  __syncthreads();
  for (int i = tid; i < B * SEQ; i += NTHR) {
    int b = i >> 6, s2 = i & 63;
    const float* er = P.h2a + (s2 + 1) * HSZ;
    const float* xb = xs + b * HSZ;
    float acc = 0.f;
    for (int e = 0; e < HSZ; e += 4) {
      float4 ev = *(const float4*)(er + e);
      acc += ev.x * xb[e] + ev.y * xb[e + 1] + ev.z * xb[e + 2] + ev.w * xb[e + 3];
    }
    at[i] = acc;
  }
  __syncthreads();
  if (tid < B) {
    float m = -INFINITY;
    for (int s2 = 0; s2 < SEQ; ++s2) m = fmaxf(m, at[tid * SEQ + s2]);
    float s = 0.f;
    for (int s2 = 0; s2 < SEQ; ++s2) { float e = expf(at[tid * SEQ + s2] - m); at[tid * SEQ + s2] = e; s += e; }
    float inv = 1.f / s;
    for (int s2 = 0; s2 < SEQ; ++s2) at[tid * SEQ + s2] *= inv;
  }
  __syncthreads();
  if (tid < 128) {
    int h4 = tid * 4;
    float4 acc[B];
#pragma unroll
    for (int b = 0; b < B; ++b) acc[b] = make_float4(0.f, 0.f, 0.f, 0.f);
    for (int s2 = 0; s2 < SEQ; ++s2) {
      float4 ev = *(const float4*)(P.h2a + (s2 + 1) * HSZ + h4);
#pragma unroll
      for (int b = 0; b < B; ++b) {
        float a = at[b * SEQ + s2];
        acc[b].x += a * ev.x; acc[b].y += a * ev.y; acc[b].z += a * ev.z; acc[b].w += a * ev.w;
      }
    }
#pragma unroll
    for (int b = 0; b < B; ++b) *(float4*)(xcs + b * 1024 + 512 + h4) = acc[b];
  }
  for (int i = tid; i < B * HSZ; i += NTHR) {
    int b = i >> 9, hcol = i & 511;
    xcs[b * 1024 + hcol] = xs[b * HSZ + hcol];
  }
  __syncthreads();
  int wave = tid >> 6, lane = tid & 63;
  int j = blk * 4 + wave;
  const float4* w = (const float4*)(P.W_c + (size_t)j * 1024);
  float4 w0 = w[lane], w1 = w[lane + 64], w2 = w[lane + 128], w3 = w[lane + 192];
#pragma unroll
  for (int b = 0; b < B; ++b) {
    const float4* xb = (const float4*)(xcs + b * 1024);
    float acc = dot4(w0, xb[lane]) + dot4(w1, xb[lane + 64]) +
                dot4(w2, xb[lane + 128]) + dot4(w3, xb[lane + 192]);
    acc = wsum(acc);
    if (lane == 0) agst(&P.feat[b * HSZ + j], tanhf(acc));
  }
}

// logits + streaming (max, sumexp, top3) per beam per block; all 256 blocks
template <int B>
__device__ void phase_logits(const Ptrs& P, float* sm, int blk, int tid) {
  float* fst = sm;  // B*HSZ
  for (int i = tid; i < B * HSZ; i += NTHR) fst[i] = agld(&P.feat[i]);
  __syncthreads();
  int wave = tid >> 6, lane = tid & 63;
  int gid  = blk * 4 + wave;  // 0..1023
  float4 f0[B], f1[B];
#pragma unroll
  for (int b = 0; b < B; ++b) {
    f0[b] = ((const float4*)(fst + b * HSZ))[lane];
    f1[b] = ((const float4*)(fst + b * HSZ))[lane + 64];
  }
  float m[B], ss[B], tv[B][3];
  int tix[B][3];
#pragma unroll
  for (int b = 0; b < B; ++b) {
    m[b] = -INFINITY; ss[b] = 0.f;
#pragma unroll
    for (int k = 0; k < 3; ++k) { tv[b][k] = -INFINITY; tix[b][k] = 0x7fffffff; }
  }
  // 1-deep row prefetch: issue next row's loads before this row's reduce
  int v = gid;
  const float4* wr = (const float4*)(P.W_out + (size_t)v * HSZ);
  float4 w0 = wr[lane], w1 = wr[lane + 64];
  float bo = P.b_out[v];
  while (v < VOC) {
    int vn = v + 1024;
    float4 n0 = make_float4(0.f, 0.f, 0.f, 0.f), n1 = n0;
    float bn = 0.f;
    if (vn < VOC) {
      const float4* wrn = (const float4*)(P.W_out + (size_t)vn * HSZ);
      n0 = wrn[lane]; n1 = wrn[lane + 64]; bn = P.b_out[vn];
    }
#pragma unroll
    for (int b = 0; b < B; ++b) {
      float acc = wsum(dot4(w0, f0[b]) + dot4(w1, f1[b])) + bo;
      float mo = m[b], mn = fmaxf(mo, acc);
      ss[b] = ss[b] * expf(mo - mn) + expf(acc - mn);
      m[b]  = mn;
      ins3(tv[b], tix[b], acc, v);
    }
    w0 = n0; w1 = n1; bo = bn; v = vn;
  }
  __shared__ float lm[4][3], lss[4][3], lv[4][3][3];
  __shared__ int li[4][3][3];
  if (lane == 0) {
#pragma unroll
    for (int b = 0; b < B; ++b) {
      lm[wave][b] = m[b]; lss[wave][b] = ss[b];
#pragma unroll
      for (int k = 0; k < 3; ++k) { lv[wave][b][k] = tv[b][k]; li[wave][b][k] = tix[b][k]; }
    }
  }
  __syncthreads();
  if (tid < B) {
    int b = tid;
    float M = fmaxf(fmaxf(lm[0][b], lm[1][b]), fmaxf(lm[2][b], lm[3][b]));
    float S = 0.f;
#pragma unroll
    for (int w2 = 0; w2 < 4; ++w2) S += lss[w2][b] * expf(lm[w2][b] - M);
    float bv[3] = {-INFINITY, -INFINITY, -INFINITY};
    int bi3[3]  = {0x7fffffff, 0x7fffffff, 0x7fffffff};
#pragma unroll
    for (int w2 = 0; w2 < 4; ++w2)
#pragma unroll
      for (int k = 0; k < 3; ++k) ins3(bv, bi3, lv[w2][b][k], li[w2][b][k]);
    int o = blk * 3 + b;
    agst(&P.pm[o], M); agst(&P.ps[o], S);
#pragma unroll
    for (int k = 0; k < 3; ++k) { agst(&P.pv[o * 3 + k], bv[k]); agsti(&P.pi[o * 3 + k], bi3[k]); }
  }
}

// final merge + beam bookkeeping; run by block 0's 256 threads inside the logits barrier
template <int B, int STEP0>
__device__ void merge_body(const Ptrs& P, int tid, int ti) {
  __shared__ float sM[3], sS[3], sV[3][3], sScore[3];
  __shared__ int sI[3][3], sOrig[3], sTokNew[3], sTokOld[3], sKstar;
  int wave = tid >> 6, lane = tid & 63;
  if (wave < B) {
    int b = wave;
    float lm4[4], ls4[4];
    float M = -INFINITY;
#pragma unroll
    for (int q = 0; q < 4; ++q) {
      int blk2 = lane + q * 64;
      lm4[q] = agld(&P.pm[blk2 * 3 + b]); ls4[q] = agld(&P.ps[blk2 * 3 + b]);
      M = fmaxf(M, lm4[q]);
    }
#pragma unroll
    for (int off = 32; off; off >>= 1) M = fmaxf(M, __shfl_xor(M, off, 64));
    float S = 0.f;
#pragma unroll
    for (int q = 0; q < 4; ++q) S += ls4[q] * expf(lm4[q] - M);
    S = wsum(S);
    float bv[3] = {-INFINITY, -INFINITY, -INFINITY};
    int bi3[3]  = {0x7fffffff, 0x7fffffff, 0x7fffffff};
#pragma unroll
    for (int q = 0; q < 4; ++q) {
      int blk2 = lane + q * 64;
#pragma unroll
      for (int k = 0; k < 3; ++k)
        ins3(bv, bi3, agld(&P.pv[(blk2 * 3 + b) * 3 + k]), agldi(&P.pi[(blk2 * 3 + b) * 3 + k]));
    }
#pragma unroll
    for (int off = 32; off; off >>= 1) {
      float ov[3]; int oi[3];
#pragma unroll
      for (int k = 0; k < 3; ++k) { ov[k] = __shfl_xor(bv[k], off, 64); oi[k] = __shfl_xor(bi3[k], off, 64); }
#pragma unroll
      for (int k = 0; k < 3; ++k) ins3(bv, bi3, ov[k], oi[k]);
    }
    if (lane == 0) {
      sM[b] = M; sS[b] = S;
#pragma unroll
      for (int k = 0; k < 3; ++k) { sV[b][k] = bv[k]; sI[b][k] = bi3[k]; }
    }
  }
  __syncthreads();
  if (tid == 0) {
    if (STEP0) {
      float off0 = -sM[0] - logf(sS[0]);
      for (int k = 0; k < 3; ++k) {
        sScore[k] = sV[0][k] + off0;
        sTokNew[k] = sI[0][k]; sOrig[k] = 0; sTokOld[k] = 0;
        P.scores[k] = sScore[k]; P.tokens[k] = sTokNew[k];
      }
    } else {
      float osc[3]; int otk[3];
      for (int b = 0; b < 3; ++b) { osc[b] = P.scores[b]; otk[b] = P.tokens[b]; sTokOld[b] = otk[b]; }
      float cum[9];
      for (int b = 0; b < 3; ++b) {
        float o = osc[b] - sM[b] - logf(sS[b]);
        for (int k = 0; k < 3; ++k) cum[b * 3 + k] = sV[b][k] + o;
      }
      bool used[9] = {false, false, false, false, false, false, false, false, false};
      for (int k = 0; k < 3; ++k) {
        int bf = 0; float bb = -INFINITY;
        for (int f = 0; f < 9; ++f)
          if (!used[f] && cum[f] > bb) { bb = cum[f]; bf = f; }  // strict > keeps lowest flat idx
        used[bf] = true;
        sScore[k] = bb;
        int ob = bf / 3;
        sOrig[k] = ob;
        sTokNew[k] = sI[ob][bf - ob * 3];
      }
      for (int k = 0; k < 3; ++k) { P.scores[k] = sScore[k]; P.tokens[k] = sTokNew[k]; }
    }
    float bb = -INFINITY; int kk = 0;
    for (int k = 0; k < 3; ++k) if (sScore[k] > bb) { bb = sScore[k]; kk = k; }
    sKstar = kk;
  }
  __syncthreads();
  for (int idx = tid; idx < 2 * 3 * HSZ; idx += NTHR) {
    int l = idx / 1536, rem = idx % 1536, k = rem / HSZ, e = rem & 511;
    int o = STEP0 ? 0 : sOrig[k];
    agst(&P.hd[l * 1536 + k * HSZ + e], agld(&P.hdn[l * 1536 + o * HSZ + e]));
    agst(&P.cd[l * 1536 + k * HSZ + e], agld(&P.cdn[l * 1536 + o * HSZ + e]));
  }
  if (STEP0) {
    int bos = P.bosp[0];
    for (int idx = tid; idx < BEAM * TMAX; idx += NTHR) P.bt[idx] = bos;  // buffer 0
  } else {
    const int* src = P.bt + (ti & 1) * (BEAM * TMAX);
    int* dst = P.bt + ((ti + 1) & 1) * (BEAM * TMAX);
    for (int idx = tid; idx < BEAM * TMAX; idx += NTHR) {
      int k = idx / TMAX, jj = idx % TMAX, o = sOrig[k];
      dst[idx] = (jj == ti + 1) ? sTokOld[o] : src[o * TMAX + jj];
    }
  }
  for (int idx = tid; idx < BEAM * HSZ; idx += NTHR) {
    int k = idx >> 9, e = idx & 511;
    agst(&P.x_dec[idx], P.emb_dec[(size_t)sTokNew[k] * HSZ + e]);
  }
  if (!STEP0 && ti == TMAX - 2) {
    __syncthreads();
    const int* dst = P.bt + ((ti + 1) & 1) * (BEAM * TMAX);
    for (int jj = tid; jj < TMAX; jj += NTHR) P.outp[jj] = dst[sKstar * TMAX + jj];
  }
}

template <int B, int STEP0>
__device__ void dstep(const Ptrs& P, float* sm, int blk, int tid, int& nb, int ti) {
  phase_dcell<B>(P, sm, P.Wih_dec, P.Whh_dec, P.b_dec, P.x_dec, P.hd, P.cd, P.hdn, P.cdn, blk, tid);
  gbar(P, blk, tid, ++nb);
  phase_dcell<B>(P, sm, P.Wih_dec + LOFF, P.Whh_dec + LOFF, P.b_dec + H4,
                 P.hdn, P.hd + 1536, P.cd + 1536, P.hdn + 1536, P.cdn + 1536, blk, tid);
  gbar(P, blk, tid, ++nb);
  phase_attfeat<B>(P, sm, blk, tid);
  gbar(P, blk, tid, ++nb);
  phase_logits<B>(P, sm, blk, tid);
  // fused barrier: block0's collect == "all partials ready"; merge runs inside
  ++nb;
  bar_arrive(P.flags, blk, tid, nb);
  if (blk == 0) {
    bar_collect(P.flags, tid, nb);
    merge_body<B, STEP0>(P, tid, ti);
    __syncthreads();
    bar_release(P.go, tid, nb);
  } else {
    bar_waitgo(P.go, blk, tid, nb);
  }
}

__global__ void __launch_bounds__(NTHR, 1) mega(Ptrs P) {
  __shared__ float sm[4800];  // shared arena, reused by all phases
  int blk = blockIdx.x, tid = threadIdx.x;
  int nb = 0;

  phase_xw1(P, blk, tid);
  gbar(P, blk, tid, ++nb);
  for (int s = 0; s <= SEQ; ++s) {
    phase_encslot(P, sm, blk, tid, s);
    ++nb;
    bar_arrive(P.flags, blk, tid, nb);
    if (blk == 0) {
      bar_collect(P.flags, tid, nb);
      if (s == SEQ) { dinit_body(P, tid); __syncthreads(); }
      bar_release(P.go, tid, nb);
    } else {
      bar_waitgo(P.go, blk, tid, nb);
    }
  }

  for (int step = 0; step < TMAX; ++step) {
    if (step == 0) dstep<1, 1>(P, sm, blk, tid, nb, -1);
    else           dstep<3, 0>(P, sm, blk, tid, nb, step - 1);
  }
}

extern "C" void kernel_launch(void* const* d_in, const int* in_sizes, int n_in,
                              void* d_out, int out_size, void* d_ws, size_t ws_size,
                              hipStream_t stream) {
  Ptrs P;
  P.seq     = (const int*)d_in[0];
  P.emb_enc = (const float*)d_in[1];
  P.Wih_enc = (const float*)d_in[2];
  P.Whh_enc = (const float*)d_in[3];
  P.b_enc   = (const float*)d_in[4];
  P.emb_dec = (const float*)d_in[5];
  P.Wih_dec = (const float*)d_in[6];
  P.Whh_dec = (const float*)d_in[7];
  P.b_dec   = (const float*)d_in[8];
  P.W_c     = (const float*)d_in[9];
  P.W_out   = (const float*)d_in[10];
  P.b_out   = (const float*)d_in[11];
  P.bosp    = (const int*)d_in[14];

  // barrier region: 256 flag lines + 16 go lines (64 B each), zeroed every call
  P.flags = (int*)d_ws;
  P.go    = (int*)d_ws + NBLK * FLS;

  float* w = (float*)d_ws + (NBLK + 16) * FLS;
  P.xp1     = w; w += SEQ * H4;
  P.h1a     = w; w += (SEQ + 1) * HSZ;
  P.c1a     = w; w += (SEQ + 1) * HSZ;
  P.h2a     = w; w += (SEQ + 1) * HSZ;
  P.c2a     = w; w += (SEQ + 1) * HSZ;
  P.hd      = w; w += 2 * BEAM * HSZ;
  P.cd      = w; w += 2 * BEAM * HSZ;
  P.hdn     = w; w += 2 * BEAM * HSZ;
  P.cdn     = w; w += 2 * BEAM * HSZ;
  P.x_dec   = w; w += BEAM * HSZ;
  P.feat    = w; w += BEAM * HSZ;
  P.pm      = w; w += NBLK * 3;
  P.ps      = w; w += NBLK * 3;
  P.pv      = w; w += NBLK * 3 * 3;
  P.scores  = w; w += 4;
  P.pi      = (int*)w; w += NBLK * 3 * 3;
  P.tokens  = (int*)w; w += 4;
  P.bt      = (int*)w; w += 2 * BEAM * TMAX + 4;
  P.outp    = (int*)d_out;

  hipMemsetAsync(d_ws, 0, (NBLK + 16) * FLS * sizeof(int), stream);
  mega<<<dim3(NBLK), dim3(NTHR), 0, stream>>>(P);
}

// Round 7
// 4467.960 us; speedup vs baseline: 1.6557x; 1.3404x over previous
//
#include <hip/hip_runtime.h>
#include <math.h>

// Problem constants (fixed by the reference module)
#define HSZ   512
#define H4    2048
#define SEQ   64
#define VOC   32000
#define BEAM  3
#define TMAX  50
#define NBLK  256
#define NTHR  512
#define FLS   16        // flag line stride in ints (64 B)

#define LOFF  ((size_t)H4 * HSZ)   // per-layer weight stride

__device__ __forceinline__ float wsum(float v) {
#pragma unroll
  for (int off = 32; off; off >>= 1) v += __shfl_xor(v, off, 64);
  return v;
}
__device__ __forceinline__ float dot4(float4 a, float4 b) {
  return a.x * b.x + a.y * b.y + a.z * b.z + a.w * b.w;
}
__device__ __forceinline__ float sigf(float x) { return 1.f / (1.f + expf(-x)); }

__device__ __forceinline__ bool better(float v1, int i1, float v2, int i2) {
  return (v1 > v2) || (v1 == v2 && i1 < i2);  // jax.lax.top_k order: value desc, index asc
}
__device__ __forceinline__ void ins3(float* v, int* idx, float nv, int ni) {
  if (better(nv, ni, v[2], idx[2])) {
    if (better(nv, ni, v[1], idx[1])) {
      v[2] = v[1]; idx[2] = idx[1];
      if (better(nv, ni, v[0], idx[0])) { v[1] = v[0]; idx[1] = idx[0]; v[0] = nv; idx[0] = ni; }
      else { v[1] = nv; idx[1] = ni; }
    } else { v[2] = nv; idx[2] = ni; }
  }
}

// ---- coherent accessors for cross-block state (relaxed, agent scope) ----
__device__ __forceinline__ float agld(const float* p) {
  return __hip_atomic_load(p, __ATOMIC_RELAXED, __HIP_MEMORY_SCOPE_AGENT);
}
__device__ __forceinline__ void agst(float* p, float v) {
  __hip_atomic_store(p, v, __ATOMIC_RELAXED, __HIP_MEMORY_SCOPE_AGENT);
}
__device__ __forceinline__ int agldi(const int* p) {
  return __hip_atomic_load(p, __ATOMIC_RELAXED, __HIP_MEMORY_SCOPE_AGENT);
}

// ---- RMW-only grid barrier (round-6 flavor, passed bit-exact) ----
__device__ __forceinline__ void rmw_set(int* p, int ep) {
  __hip_atomic_fetch_max(p, ep, __ATOMIC_RELAXED, __HIP_MEMORY_SCOPE_AGENT);
}
__device__ __forceinline__ int rmw_get(int* p) {
  return __hip_atomic_fetch_add(p, 0, __ATOMIC_RELAXED, __HIP_MEMORY_SCOPE_AGENT);
}
__device__ __forceinline__ void bar_arrive(int* flags, int blk, int tid, int ep) {
  __syncthreads();  // compiler emits waitcnt vmcnt(0) before s_barrier => stores at L3
  if (tid == 0) rmw_set(&flags[blk * FLS], ep);
}
__device__ __forceinline__ void bar_collect(int* flags, int tid, int ep) {
  if (tid < NBLK) {
    long it = 0;
    while (rmw_get(&flags[tid * FLS]) < ep && it < 100000000L) ++it;
  }
  asm volatile("" ::: "memory");
  __syncthreads();
}
__device__ __forceinline__ void bar_release(int* go, int tid, int ep) {
  if (tid < 16) rmw_set(&go[tid * FLS], ep);
}
__device__ __forceinline__ void bar_waitgo(int* go, int blk, int tid, int ep) {
  if (tid == 0) {
    long it = 0;
    while (rmw_get(&go[(blk & 15) * FLS]) < ep && it < 100000000L) {
      __builtin_amdgcn_s_sleep(1); ++it;
    }
  }
  asm volatile("" ::: "memory");
  __syncthreads();
}

struct Ptrs {
  const int*   seq;
  const float* emb_enc; const float* Wih_enc; const float* Whh_enc; const float* b_enc;
  const float* emb_dec; const float* Wih_dec; const float* Whh_dec; const float* b_dec;
  const float* W_c; const float* W_out; const float* b_out;
  const int*   bosp;
  int* flags; int* go;
  float* xp1;
  float* h1a; float* c1a; float* h2a; float* c2a;
  float* hd; float* cd; float* hdn; float* cdn;
  float* x_dec; float* feat;
  float* pm; float* ps; float* pv; int* pi;
  float* scores; int* tokens; int* bt;
  int* outp;
};

__device__ __forceinline__ void gbar(const Ptrs& P, int blk, int tid, int ep) {
  bar_arrive(P.flags, blk, tid, ep);
  if (blk == 0) {
    bar_collect(P.flags, tid, ep);
    bar_release(P.go, tid, ep);
  } else {
    bar_waitgo(P.go, blk, tid, ep);
  }
}

// ---------------- encoder phases ----------------

// xp1[t][r] = b_enc[r] + dot(Wih_enc[r], emb_enc[seq[t]]); wave owns row r, lane owns t
__device__ void phase_xw1(const Ptrs& P, int blk, int tid) {
  int t    = tid & 63;
  int wave = tid >> 6;
  int r    = blk * 8 + wave;
  int tok  = P.seq[t];
  const float* xr = P.emb_enc + (size_t)tok * HSZ;
  const float* wr = P.Wih_enc + (size_t)r * HSZ;
  float acc = 0.f;
  for (int e = 0; e < HSZ; e += 4) {
    float4 wv = *(const float4*)(wr + e);
    float4 xv = *(const float4*)(xr + e);
    acc += dot4(wv, xv);
  }
  agst(&P.xp1[t * H4 + r], acc + P.b_enc[r]);
}

// One wavefront slot: layer1 cell t=s (blocks 0..127), layer2 cell t=s-1 (blocks 128..255).
// 4 rows/block, 2 gates/wave; gates recombined in LDS. Per-gate math bit-identical to r6.
__device__ void phase_encslot(const Ptrs& P, float* sm, int blk, int tid, int s) {
  int wave = tid >> 6, lane = tid & 63;
  bool l2  = blk >= 128;
  int t    = l2 ? s - 1 : s;
  if (t < 0 || t >= SEQ) return;
  int bb   = blk & 127;
  int lr   = wave >> 1;            // 0..3 local row
  int j    = bb * 4 + lr;          // 0..511
  int g0   = (wave & 1) * 2;       // gates {g0, g0+1}
  float* rowX = sm;                // 512
  float* rowH = sm + 512;          // 512 (l2 only)
  float* zl   = sm + 1024;         // [4][4]
  if (!l2) {
    rowX[tid < HSZ ? tid : 0] = 0.f;  // dummy for tid>=512 impossible (NTHR=512)
    rowX[tid] = (t > 0) ? agld(&P.h1a[t * HSZ + tid]) : 0.f;
    __syncthreads();
    float4 h0 = ((const float4*)rowX)[lane], h1v = ((const float4*)rowX)[lane + 64];
#pragma unroll
    for (int gg = 0; gg < 2; ++gg) {
      int g = g0 + gg;
      int row = j + (g << 9);
      const float4* wr = (const float4*)(P.Whh_enc + (size_t)row * HSZ);
      float zs = wsum(dot4(wr[lane], h0) + dot4(wr[lane + 64], h1v));
      if (lane == 0) zl[lr * 4 + g] = zs + agld(&P.xp1[t * H4 + row]);
    }
    __syncthreads();
    if (tid < 4) {
      int j2 = bb * 4 + tid;
      float z0 = zl[tid * 4 + 0], z1 = zl[tid * 4 + 1], z2 = zl[tid * 4 + 2], z3 = zl[tid * 4 + 3];
      float cp = (t > 0) ? agld(&P.c1a[t * HSZ + j2]) : 0.f;
      float c = sigf(z1) * cp + sigf(z0) * tanhf(z2);
      agst(&P.c1a[(t + 1) * HSZ + j2], c);
      agst(&P.h1a[(t + 1) * HSZ + j2], sigf(z3) * tanhf(c));
    }
  } else {
    rowX[tid] = agld(&P.h1a[(t + 1) * HSZ + tid]);
    rowH[tid] = (t > 0) ? agld(&P.h2a[t * HSZ + tid]) : 0.f;
    __syncthreads();
    float4 x0 = ((const float4*)rowX)[lane], x1 = ((const float4*)rowX)[lane + 64];
    float4 h0 = ((const float4*)rowH)[lane], h1v = ((const float4*)rowH)[lane + 64];
#pragma unroll
    for (int gg = 0; gg < 2; ++gg) {
      int g = g0 + gg;
      int row = j + (g << 9);
      const float4* wi = (const float4*)(P.Wih_enc + LOFF + (size_t)row * HSZ);
      const float4* wh = (const float4*)(P.Whh_enc + LOFF + (size_t)row * HSZ);
      float zs = wsum(dot4(wi[lane], x0) + dot4(wi[lane + 64], x1) +
                      dot4(wh[lane], h0) + dot4(wh[lane + 64], h1v));
      if (lane == 0) zl[lr * 4 + g] = zs + P.b_enc[H4 + row];
    }
    __syncthreads();
    if (tid < 4) {
      int j2 = bb * 4 + tid;
      float z0 = zl[tid * 4 + 0], z1 = zl[tid * 4 + 1], z2 = zl[tid * 4 + 2], z3 = zl[tid * 4 + 3];
      float cp = (t > 0) ? agld(&P.c2a[t * HSZ + j2]) : 0.f;
      float c = sigf(z1) * cp + sigf(z0) * tanhf(z2);
      agst(&P.c2a[(t + 1) * HSZ + j2], c);
      agst(&P.h2a[(t + 1) * HSZ + j2], sigf(z3) * tanhf(c));
    }
  }
}

// run by block 0 inside the last encoder slot's barrier
__device__ void dinit_body(const Ptrs& P, int tid) {
  int bos = P.bosp[0];
  for (int e = tid; e < HSZ; e += NTHR) {
    agst(&P.hd[e],        agld(&P.h1a[SEQ * HSZ + e]));
    agst(&P.cd[e],        agld(&P.c1a[SEQ * HSZ + e]));
    agst(&P.hd[1536 + e], agld(&P.h2a[SEQ * HSZ + e]));
    agst(&P.cd[1536 + e], agld(&P.c2a[SEQ * HSZ + e]));
    agst(&P.x_dec[e],     P.emb_dec[(size_t)bos * HSZ + e]);
  }
}

// ---------------- decoder phases ----------------

// one (row, gate) per wave across all 256 blocks x 8 waves = 2048 waves = 512 rows x 4 gates
template <int B>
__device__ void phase_dcell(const Ptrs& P, float* sm,
                            const float* __restrict__ Wih, const float* __restrict__ Whh,
                            const float* __restrict__ bias, const float* x,
                            const float* hin, const float* cin,
                            float* hout, float* cout, int blk, int tid) {
  float* xl = sm;
  float* hl = sm + B * HSZ;
  float* cl = sm + 2 * B * HSZ;
  float* zl = sm + 3 * B * HSZ;  // [2][4][B]
  for (int i = tid; i < B * HSZ; i += NTHR) {
    xl[i] = agld(&x[i]); hl[i] = agld(&hin[i]); cl[i] = agld(&cin[i]);
  }
  __syncthreads();
  int wave = tid >> 6, lane = tid & 63;
  int lr = wave >> 2;          // 0..1
  int g  = wave & 3;           // gate
  int j  = blk * 2 + lr;       // row 0..511
  int row = j + (g << 9);
  const float4* wi = (const float4*)(Wih + (size_t)row * HSZ);
  const float4* wh = (const float4*)(Whh + (size_t)row * HSZ);
  float4 wi0 = wi[lane], wi1 = wi[lane + 64], wh0 = wh[lane], wh1 = wh[lane + 64];
  float bb = bias[row];
#pragma unroll
  for (int b = 0; b < B; ++b) {
    float4 xv0 = ((const float4*)(xl + b * HSZ))[lane];
    float4 xv1 = ((const float4*)(xl + b * HSZ))[lane + 64];
    float4 hv0 = ((const float4*)(hl + b * HSZ))[lane];
    float4 hv1 = ((const float4*)(hl + b * HSZ))[lane + 64];
    float acc = dot4(wi0, xv0) + dot4(wi1, xv1) + dot4(wh0, hv0) + dot4(wh1, hv1);
    float z = wsum(acc) + bb;
    if (lane == 0) zl[(lr * 4 + g) * B + b] = z;
  }
  __syncthreads();
  for (int q = tid; q < 2 * B; q += NTHR) {
    int lr2 = q / B, b = q % B;
    int j2 = blk * 2 + lr2;
    float z0 = zl[(lr2 * 4 + 0) * B + b], z1 = zl[(lr2 * 4 + 1) * B + b];
    float z2 = zl[(lr2 * 4 + 2) * B + b], z3 = zl[(lr2 * 4 + 3) * B + b];
    float c = sigf(z1) * cl[b * HSZ + j2] + sigf(z0) * tanhf(z2);
    agst(&cout[b * HSZ + j2], c);
    agst(&hout[b * HSZ + j2], sigf(z3) * tanhf(c));
  }
}

// attention + context + feat; blocks 0..63 (8 waves x 64 = 512 feat rows)
template <int B>
__device__ void phase_attfeat(const Ptrs& P, float* sm, int blk, int tid) {
  if (blk >= 64) return;  // block-uniform
  float* xs  = sm;            // B*HSZ
  float* at  = sm + 1536;     // B*SEQ
  float* xcs = sm + 1728;     // B*1024
  for (int i = tid; i < B * HSZ; i += NTHR) xs[i] = agld(&P.hdn[1536 + i]);
  __syncthreads();
  if (tid < B * SEQ) {
    int b = tid >> 6, s2 = tid & 63;
    const float* er = P.h2a + (s2 + 1) * HSZ;
    const float* xb = xs + b * HSZ;
    float acc = 0.f;
    for (int e = 0; e < HSZ; e += 4) {
      float4 ev = *(const float4*)(er + e);
      acc += ev.x * xb[e] + ev.y * xb[e + 1] + ev.z * xb[e + 2] + ev.w * xb[e + 3];
    }
    at[tid] = acc;
  }
  __syncthreads();
  if (tid < B) {
    float m = -INFINITY;
    for (int s2 = 0; s2 < SEQ; ++s2) m = fmaxf(m, at[tid * SEQ + s2]);
    float s = 0.f;
    for (int s2 = 0; s2 < SEQ; ++s2) { float e = expf(at[tid * SEQ + s2] - m); at[tid * SEQ + s2] = e; s += e; }
    float inv = 1.f / s;
    for (int s2 = 0; s2 < SEQ; ++s2) at[tid * SEQ + s2] *= inv;
  }
  __syncthreads();
  if (tid < 128) {
    int h4 = tid * 4;
    float4 acc[B];
#pragma unroll
    for (int b = 0; b < B; ++b) acc[b] = make_float4(0.f, 0.f, 0.f, 0.f);
    for (int s2 = 0; s2 < SEQ; ++s2) {
      float4 ev = *(const float4*)(P.h2a + (s2 + 1) * HSZ + h4);
#pragma unroll
      for (int b = 0; b < B; ++b) {
        float a = at[b * SEQ + s2];
        acc[b].x += a * ev.x; acc[b].y += a * ev.y; acc[b].z += a * ev.z; acc[b].w += a * ev.w;
      }
    }
#pragma unroll
    for (int b = 0; b < B; ++b) *(float4*)(xcs + b * 1024 + 512 + h4) = acc[b];
  }
  for (int i = tid; i < B * HSZ; i += NTHR) {
    int b = i >> 9, hcol = i & 511;
    xcs[b * 1024 + hcol] = xs[b * HSZ + hcol];
  }
  __syncthreads();
  int wave = tid >> 6, lane = tid & 63;
  int j = blk * 8 + wave;  // 0..511
  const float4* w = (const float4*)(P.W_c + (size_t)j * 1024);
  float4 w0 = w[lane], w1 = w[lane + 64], w2 = w[lane + 128], w3 = w[lane + 192];
#pragma unroll
  for (int b = 0; b < B; ++b) {
    const float4* xb = (const float4*)(xcs + b * 1024);
    float acc = dot4(w0, xb[lane]) + dot4(w1, xb[lane + 64]) +
                dot4(w2, xb[lane + 128]) + dot4(w3, xb[lane + 192]);
    acc = wsum(acc);
    if (lane == 0) agst(&P.feat[b * HSZ + j], tanhf(acc));
  }
}

// logits + streaming (max, sumexp, top3); 2048 wave-slots, 16 rows each, 4-row batched loads
template <int B>
__device__ void phase_logits(const Ptrs& P, float* sm, int blk, int tid) {
  float* fst = sm;  // B*HSZ
  for (int i = tid; i < B * HSZ; i += NTHR) fst[i] = agld(&P.feat[i]);
  __syncthreads();
  int wave = tid >> 6, lane = tid & 63;
  int gid  = blk * 8 + wave;  // 0..2047
  float4 f0[B], f1[B];
#pragma unroll
  for (int b = 0; b < B; ++b) {
    f0[b] = ((const float4*)(fst + b * HSZ))[lane];
    f1[b] = ((const float4*)(fst + b * HSZ))[lane + 64];
  }
  float m[B], ss[B], tv[B][3];
  int tix[B][3];
#pragma unroll
  for (int b = 0; b < B; ++b) {
    m[b] = -INFINITY; ss[b] = 0.f;
#pragma unroll
    for (int k = 0; k < 3; ++k) { tv[b][k] = -INFINITY; tix[b][k] = 0x7fffffff; }
  }
  for (int k0 = 0; k0 < 16; k0 += 4) {
    float4 a0[4], a1[4]; float ab[4]; int vr[4];
#pragma unroll
    for (int u = 0; u < 4; ++u) {
      int v = gid + (k0 + u) * 2048;
      vr[u] = v;
      if (v < VOC) {
        const float4* wr = (const float4*)(P.W_out + (size_t)v * HSZ);
        a0[u] = wr[lane]; a1[u] = wr[lane + 64]; ab[u] = P.b_out[v];
      } else {
        a0[u] = make_float4(0.f, 0.f, 0.f, 0.f); a1[u] = a0[u]; ab[u] = 0.f;
      }
    }
#pragma unroll
    for (int u = 0; u < 4; ++u) {
      if (vr[u] >= VOC) continue;  // wave-uniform
#pragma unroll
      for (int b = 0; b < B; ++b) {
        float acc = wsum(dot4(a0[u], f0[b]) + dot4(a1[u], f1[b])) + ab[u];
        float mo = m[b], mn = fmaxf(mo, acc);
        ss[b] = ss[b] * expf(mo - mn) + expf(acc - mn);
        m[b]  = mn;
        ins3(tv[b], tix[b], acc, vr[u]);
      }
    }
  }
  __shared__ float lm[8][3], lss[8][3], lv[8][3][3];
  __shared__ int li[8][3][3];
  if (lane == 0) {
#pragma unroll
    for (int b = 0; b < B; ++b) {
      lm[wave][b] = m[b]; lss[wave][b] = ss[b];
#pragma unroll
      for (int k = 0; k < 3; ++k) { lv[wave][b][k] = tv[b][k]; li[wave][b][k] = tix[b][k]; }
    }
  }
  __syncthreads();
  if (tid < B) {
    int b = tid;
    float M = -INFINITY;
#pragma unroll
    for (int w2 = 0; w2 < 8; ++w2) M = fmaxf(M, lm[w2][b]);
    float S = 0.f;
#pragma unroll
    for (int w2 = 0; w2 < 8; ++w2) S += lss[w2][b] * expf(lm[w2][b] - M);
    float bv[3] = {-INFINITY, -INFINITY, -INFINITY};
    int bi3[3]  = {0x7fffffff, 0x7fffffff, 0x7fffffff};
#pragma unroll
    for (int w2 = 0; w2 < 8; ++w2)
#pragma unroll
      for (int k = 0; k < 3; ++k) ins3(bv, bi3, lv[w2][b][k], li[w2][b][k]);
    int o = blk * 3 + b;
    agst(&P.pm[o], M); agst(&P.ps[o], S);
#pragma unroll
    for (int k = 0; k < 3; ++k) {
      agst(&P.pv[o * 3 + k], bv[k]);
      __hip_atomic_store(&P.pi[o * 3 + k], bi3[k], __ATOMIC_RELAXED, __HIP_MEMORY_SCOPE_AGENT);
    }
  }
}

// final merge + beam bookkeeping; block 0 inside the fused logits barrier
template <int B, int STEP0>
__device__ void merge_body(const Ptrs& P, int tid, int ti) {
  __shared__ float sM[3], sS[3], sV[3][3], sScore[3];
  __shared__ int sI[3][3], sOrig[3], sTokNew[3], sTokOld[3], sKstar;
  int wave = tid >> 6, lane = tid & 63;
  if (wave < B) {
    int b = wave;
    float lm4[4], ls4[4];
    float M = -INFINITY;
#pragma unroll
    for (int q = 0; q < 4; ++q) {
      int blk2 = lane + q * 64;
      lm4[q] = agld(&P.pm[blk2 * 3 + b]); ls4[q] = agld(&P.ps[blk2 * 3 + b]);
      M = fmaxf(M, lm4[q]);
    }
#pragma unroll
    for (int off = 32; off; off >>= 1) M = fmaxf(M, __shfl_xor(M, off, 64));
    float S = 0.f;
#pragma unroll
    for (int q = 0; q < 4; ++q) S += ls4[q] * expf(lm4[q] - M);
    S = wsum(S);
    float bv[3] = {-INFINITY, -INFINITY, -INFINITY};
    int bi3[3]  = {0x7fffffff, 0x7fffffff, 0x7fffffff};
#pragma unroll
    for (int q = 0; q < 4; ++q) {
      int blk2 = lane + q * 64;
#pragma unroll
      for (int k = 0; k < 3; ++k)
        ins3(bv, bi3, agld(&P.pv[(blk2 * 3 + b) * 3 + k]), agldi(&P.pi[(blk2 * 3 + b) * 3 + k]));
    }
#pragma unroll
    for (int off = 32; off; off >>= 1) {
      float ov[3]; int oi[3];
#pragma unroll
      for (int k = 0; k < 3; ++k) { ov[k] = __shfl_xor(bv[k], off, 64); oi[k] = __shfl_xor(bi3[k], off, 64); }
#pragma unroll
      for (int k = 0; k < 3; ++k) ins3(bv, bi3, ov[k], oi[k]);
    }
    if (lane == 0) {
      sM[b] = M; sS[b] = S;
#pragma unroll
      for (int k = 0; k < 3; ++k) { sV[b][k] = bv[k]; sI[b][k] = bi3[k]; }
    }
  }
  __syncthreads();
  if (tid == 0) {
    if (STEP0) {
      float off0 = -sM[0] - logf(sS[0]);
      for (int k = 0; k < 3; ++k) {
        sScore[k] = sV[0][k] + off0;
        sTokNew[k] = sI[0][k]; sOrig[k] = 0; sTokOld[k] = 0;
        P.scores[k] = sScore[k]; P.tokens[k] = sTokNew[k];
      }
    } else {
      float osc[3]; int otk[3];
      for (int b = 0; b < 3; ++b) { osc[b] = P.scores[b]; otk[b] = P.tokens[b]; sTokOld[b] = otk[b]; }
      float cum[9];
      for (int b = 0; b < 3; ++b) {
        float o = osc[b] - sM[b] - logf(sS[b]);
        for (int k = 0; k < 3; ++k) cum[b * 3 + k] = sV[b][k] + o;
      }
      bool used[9] = {false, false, false, false, false, false, false, false, false};
      for (int k = 0; k < 3; ++k) {
        int bf = 0; float bb = -INFINITY;
        for (int f = 0; f < 9; ++f)
          if (!used[f] && cum[f] > bb) { bb = cum[f]; bf = f; }  // strict > keeps lowest flat idx
        used[bf] = true;
        sScore[k] = bb;
        int ob = bf / 3;
        sOrig[k] = ob;
        sTokNew[k] = sI[ob][bf - ob * 3];
      }
      for (int k = 0; k < 3; ++k) { P.scores[k] = sScore[k]; P.tokens[k] = sTokNew[k]; }
    }
    float bb = -INFINITY; int kk = 0;
    for (int k = 0; k < 3; ++k) if (sScore[k] > bb) { bb = sScore[k]; kk = k; }
    sKstar = kk;
  }
  __syncthreads();
  for (int idx = tid; idx < 2 * 3 * HSZ; idx += NTHR) {
    int l = idx / 1536, rem = idx % 1536, k = rem / HSZ, e = rem & 511;
    int o = STEP0 ? 0 : sOrig[k];
    agst(&P.hd[l * 1536 + k * HSZ + e], agld(&P.hdn[l * 1536 + o * HSZ + e]));
    agst(&P.cd[l * 1536 + k * HSZ + e], agld(&P.cdn[l * 1536 + o * HSZ + e]));
  }
  if (STEP0) {
    int bos = P.bosp[0];
    for (int idx = tid; idx < BEAM * TMAX; idx += NTHR) P.bt[idx] = bos;  // buffer 0
  } else {
    const int* src = P.bt + (ti & 1) * (BEAM * TMAX);
    int* dst = P.bt + ((ti + 1) & 1) * (BEAM * TMAX);
    for (int idx = tid; idx < BEAM * TMAX; idx += NTHR) {
      int k = idx / TMAX, jj = idx % TMAX, o = sOrig[k];
      dst[idx] = (jj == ti + 1) ? sTokOld[o] : src[o * TMAX + jj];
    }
  }
  for (int idx = tid; idx < BEAM * HSZ; idx += NTHR) {
    int k = idx >> 9, e = idx & 511;
    agst(&P.x_dec[idx], P.emb_dec[(size_t)sTokNew[k] * HSZ + e]);
  }
  if (!STEP0 && ti == TMAX - 2) {
    __syncthreads();
    const int* dst = P.bt + ((ti + 1) & 1) * (BEAM * TMAX);
    for (int jj = tid; jj < TMAX; jj += NTHR) P.outp[jj] = dst[sKstar * TMAX + jj];
  }
}

template <int B, int STEP0>
__device__ void dstep(const Ptrs& P, float* sm, int blk, int tid, int& nb, int ti) {
  phase_dcell<B>(P, sm, P.Wih_dec, P.Whh_dec, P.b_dec, P.x_dec, P.hd, P.cd, P.hdn, P.cdn, blk, tid);
  gbar(P, blk, tid, ++nb);
  phase_dcell<B>(P, sm, P.Wih_dec + LOFF, P.Whh_dec + LOFF, P.b_dec + H4,
                 P.hdn, P.hd + 1536, P.cd + 1536, P.hdn + 1536, P.cdn + 1536, blk, tid);
  gbar(P, blk, tid, ++nb);
  phase_attfeat<B>(P, sm, blk, tid);
  gbar(P, blk, tid, ++nb);
  phase_logits<B>(P, sm, blk, tid);
  // fused barrier: block0's collect == "all partials ready"; merge runs inside
  ++nb;
  bar_arrive(P.flags, blk, tid, nb);
  if (blk == 0) {
    bar_collect(P.flags, tid, nb);
    merge_body<B, STEP0>(P, tid, ti);
    __syncthreads();
    bar_release(P.go, tid, nb);
  } else {
    bar_waitgo(P.go, blk, tid, nb);
  }
}

__global__ void __launch_bounds__(NTHR) mega(Ptrs P) {
  __shared__ float sm[4832];  // shared arena, reused by all phases
  int blk = blockIdx.x, tid = threadIdx.x;
  int nb = 0;

  phase_xw1(P, blk, tid);
  gbar(P, blk, tid, ++nb);
  for (int s = 0; s <= SEQ; ++s) {
    phase_encslot(P, sm, blk, tid, s);
    ++nb;
    bar_arrive(P.flags, blk, tid, nb);
    if (blk == 0) {
      bar_collect(P.flags, tid, nb);
      if (s == SEQ) { dinit_body(P, tid); __syncthreads(); }
      bar_release(P.go, tid, nb);
    } else {
      bar_waitgo(P.go, blk, tid, nb);
    }
  }

  for (int step = 0; step < TMAX; ++step) {
    if (step == 0) dstep<1, 1>(P, sm, blk, tid, nb, -1);
    else           dstep<3, 0>(P, sm, blk, tid, nb, step - 1);
  }
}

extern "C" void kernel_launch(void* const* d_in, const int* in_sizes, int n_in,
                              void* d_out, int out_size, void* d_ws, size_t ws_size,
                              hipStream_t stream) {
  Ptrs P;
  P.seq     = (const int*)d_in[0];
  P.emb_enc = (const float*)d_in[1];
  P.Wih_enc = (const float*)d_in[2];
  P.Whh_enc = (const float*)d_in[3];
  P.b_enc   = (const float*)d_in[4];
  P.emb_dec = (const float*)d_in[5];
  P.Wih_dec = (const float*)d_in[6];
  P.Whh_dec = (const float*)d_in[7];
  P.b_dec   = (const float*)d_in[8];
  P.W_c     = (const float*)d_in[9];
  P.W_out   = (const float*)d_in[10];
  P.b_out   = (const float*)d_in[11];
  P.bosp    = (const int*)d_in[14];

  // barrier region: 256 flag lines + 16 go lines (64 B each), zeroed every call
  P.flags = (int*)d_ws;
  P.go    = (int*)d_ws + NBLK * FLS;

  float* w = (float*)d_ws + (NBLK + 16) * FLS;
  P.xp1     = w; w += SEQ * H4;
  P.h1a     = w; w += (SEQ + 1) * HSZ;
  P.c1a     = w; w += (SEQ + 1) * HSZ;
  P.h2a     = w; w += (SEQ + 1) * HSZ;
  P.c2a     = w; w += (SEQ + 1) * HSZ;
  P.hd      = w; w += 2 * BEAM * HSZ;
  P.cd      = w; w += 2 * BEAM * HSZ;
  P.hdn     = w; w += 2 * BEAM * HSZ;
  P.cdn     = w; w += 2 * BEAM * HSZ;
  P.x_dec   = w; w += BEAM * HSZ;
  P.feat    = w; w += BEAM * HSZ;
  P.pm      = w; w += NBLK * 3;
  P.ps      = w; w += NBLK * 3;
  P.pv      = w; w += NBLK * 3 * 3;
  P.scores  = w; w += 4;
  P.pi      = (int*)w; w += NBLK * 3 * 3;
  P.tokens  = (int*)w; w += 4;
  P.bt      = (int*)w; w += 2 * BEAM * TMAX + 4;
  P.outp    = (int*)d_out;

  hipMemsetAsync(d_ws, 0, (NBLK + 16) * FLS * sizeof(int), stream);
  mega<<<dim3(NBLK), dim3(NTHR), 0, stream>>>(P);
}